// Round 8
// baseline (438.374 us; speedup 1.0000x reference)
//
#include <hip/hip_runtime.h>
#include <hip/hip_bf16.h>
#include <cstdint>
#include <cstddef>

#define ALPHA_ 0.1f

static inline int cdiv(int a, int b) { return (a + b - 1) / b; }

typedef __attribute__((ext_vector_type(8))) short short8;
typedef __attribute__((ext_vector_type(4))) short short4v;
typedef __attribute__((ext_vector_type(4))) float float4v;

struct P8 { float* p[8]; };

// ---------------- WtT builder: tile-major bf16 transpose of W (K x 128) ----------------
// 32-k tile s: element (k, c) -> WtT[s*4096 + c*32 + (k - s*32)], zero-pad k>=K.
__global__ __launch_bounds__(256) void make_wtT(const float* __restrict__ W,
                                                __hip_bfloat16* __restrict__ WtT,
                                                int K)
{
  __shared__ float tile[32][129];
  const int t  = threadIdx.x;
  const int s  = blockIdx.x;
  const int k0 = s * 32;
#pragma unroll
  for (int pass = 0; pass < 16; ++pass) {
    int idx = pass * 256 + t;
    int k = idx >> 7, c = idx & 127;
    tile[k][c] = (k0 + k < K) ? W[(size_t)(k0 + k) * 128 + c] : 0.f;
  }
  __syncthreads();
#pragma unroll
  for (int pass = 0; pass < 16; ++pass) {
    int idx = pass * 256 + t;
    int c = idx >> 5, kl = idx & 31;
    WtT[(size_t)s * 4096 + c * 32 + kl] = __float2bfloat16(tile[kl][c]);
  }
}

// ---------------- init GEMM: no LDS, no barriers, BK=128, A+W direct to VGPR ----------
// Block 256 thr = 4 waves: wave (rg, ch) covers rows rb*32+rg*16..+16, cols ch*64..+64.
// Per step (128 k): lane loads 8x float4 of A (4-lane groups tile each row's 512B
// contiguously) and 16x short8 of W from tile-major WtT (L2-hot). Ping-pong A regs.
template<int KSPLIT>
__global__ __launch_bounds__(256, 3) void init_mfma3(
    const float* __restrict__ Am, const __hip_bfloat16* __restrict__ Wtm, int Nm_, int nbm, int Kpm,
    const float* __restrict__ Ad, const __hip_bfloat16* __restrict__ Wtd, int Nd_, int Kpd,
    P8 parr)
{
  const int lane = threadIdx.x & 63;
  const int wv   = threadIdx.x >> 6;
  const int rg   = wv >> 1;          // row-group 0..1
  const int ch   = wv & 1;           // col-half 0..1

  const int chunk = blockIdx.x % KSPLIT;
  int mb          = blockIdx.x / KSPLIT;

  const float* A; const __hip_bfloat16* Wt; int N, K, Kpad, rowoff, rb;
  if (mb < nbm) { A = Am; Wt = Wtm; N = Nm_; K = Nm_; Kpad = Kpm; rowoff = 0;   rb = mb; }
  else          { A = Ad; Wt = Wtd; N = Nd_; K = Nd_; Kpad = Kpd; rowoff = Nm_; rb = mb - nbm; }

  float* Cp = parr.p[chunk];

  const int St = Kpad / 128;
  const int s0 = (int)(((long)St * chunk) / KSPLIT);
  const int s1 = (int)(((long)St * (chunk + 1)) / KSPLIT);

  const int rloc = lane & 15;
  const int kq   = lane >> 4;        // 0..3
  const int kq8  = kq * 8;
  const int row  = rb * 32 + rg * 16 + rloc;
  const int ra   = (row < N) ? row : (N - 1);
  const float* abase = A + (size_t)ra * K;
  const int kclamp = K - 4;

  // W per-lane byte offsets within a 32-k tile (8192 B): col*64 + kq*16
  int wcol[4];
#pragma unroll
  for (int mt = 0; mt < 4; ++mt)
    wcol[mt] = (ch * 64 + mt * 16 + rloc) * 64 + kq * 16;
  const char* wbase = (const char*)Wt;

  float4v acc[4];
#pragma unroll
  for (int mt = 0; mt < 4; ++mt) acc[mt] = (float4v){0.f, 0.f, 0.f, 0.f};

  float4v a0[8], a1[8];

#define LOADA(s_, arr)                                                          \
  { _Pragma("unroll")                                                           \
    for (int kh = 0; kh < 4; ++kh) {                                            \
      int kb = (s_) * 128 + kh * 32 + kq8;                                      \
      int k0_ = kb     > kclamp ? kclamp : kb;                                  \
      int k1_ = kb + 4 > kclamp ? kclamp : kb + 4;                              \
      arr[2 * kh]     = *(const float4v*)(abase + k0_);                         \
      arr[2 * kh + 1] = *(const float4v*)(abase + k1_);                         \
    } }

#define COMPUTE(s_, arr)                                                        \
  { _Pragma("unroll")                                                           \
    for (int kh = 0; kh < 4; ++kh) {                                            \
      union { short8 v; __hip_bfloat16 h[8]; } f_;                              \
      f_.h[0] = __float2bfloat16(arr[2*kh].x);                                  \
      f_.h[1] = __float2bfloat16(arr[2*kh].y);                                  \
      f_.h[2] = __float2bfloat16(arr[2*kh].z);                                  \
      f_.h[3] = __float2bfloat16(arr[2*kh].w);                                  \
      f_.h[4] = __float2bfloat16(arr[2*kh+1].x);                                \
      f_.h[5] = __float2bfloat16(arr[2*kh+1].y);                                \
      f_.h[6] = __float2bfloat16(arr[2*kh+1].z);                                \
      f_.h[7] = __float2bfloat16(arr[2*kh+1].w);                                \
      const char* wt_ = wbase + (size_t)((s_) * 4 + kh) * 8192;                 \
      _Pragma("unroll")                                                         \
      for (int mt = 0; mt < 4; ++mt) {                                          \
        short8 w_ = *(const short8*)(wt_ + wcol[mt]);                           \
        acc[mt] = __builtin_amdgcn_mfma_f32_16x16x32_bf16(w_, f_.v, acc[mt], 0, 0, 0); \
      } } }

  int s = s0;
  LOADA(s, a0);
  while (s + 2 <= s1) {
    LOADA(s + 1, a1);
    COMPUTE(s, a0);
    if (s + 2 < s1) LOADA(s + 2, a0);
    COMPUTE(s + 1, a1);
    s += 2;
  }
  if (s < s1) COMPUTE(s, a0);

  if (row < N) {
    float* dst = Cp + (size_t)(rowoff + row) * 128 + ch * 64 + kq * 4;
#pragma unroll
    for (int mt = 0; mt < 4; ++mt)
      *(float4v*)(dst + mt * 16) = acc[mt];
  }
#undef LOADA
#undef COMPUTE
}

// sum NP partials -> init (f32) + both state sections (bf16)
template<int NP>
__global__ __launch_bounds__(256) void combineN(
    P8 parr, float4v* __restrict__ o_init, __hip_bfloat16* __restrict__ state,
    int n4, int NtD)
{
  int i = blockIdx.x * 256 + threadIdx.x;
  if (i >= n4) return;
  float4v s = ((const float4v*)parr.p[0])[i];
#pragma unroll
  for (int j = 1; j < NP; ++j) {
    float4v x = ((const float4v*)parr.p[j])[i];
    s.x += x.x; s.y += x.y; s.z += x.z; s.w += x.w;
  }
  o_init[i] = s;
  union { short4v v; __hip_bfloat16 h[4]; } b;
  b.h[0] = __float2bfloat16(s.x); b.h[1] = __float2bfloat16(s.y);
  b.h[2] = __float2bfloat16(s.z); b.h[3] = __float2bfloat16(s.w);
  *(short4v*)(state + (size_t)i * 4) = b.v;
  *(short4v*)(state + (size_t)NtD + (size_t)i * 4) = b.v;
}

// ---------------- unified gather (state in bf16), unrolled over P and L ----------------
template<int L, int PP>
__device__ __forceinline__ float gath(const __hip_bfloat16* __restrict__ sect,
                                      const int* __restrict__ paths,
                                      const float* __restrict__ pw, int n, int N, int d)
{
  float pwv[L];
#pragma unroll
  for (int l = 0; l < L; ++l) pwv[l] = pw[l * 128 + d];
  float acc = 0.f;
  const int* ip0 = paths + (size_t)n * L;
#pragma unroll
  for (int p = 0; p < PP; ++p) {
    const int* ip = ip0 + (size_t)p * N * L;   // wave-uniform -> scalar loads
    int idx[L];
#pragma unroll
    for (int l = 0; l < L; ++l) idx[l] = ip[l];
#pragma unroll
    for (int l = 0; l < L; ++l)
      acc = fmaf(pwv[l], __bfloat162float(sect[(size_t)idx[l] * 128 + d]), acc);
  }
  return acc;
}

template<int LMM, int LMD, int PP>
__global__ __launch_bounds__(256) void gather_all(
    const __hip_bfloat16* __restrict__ state,
    const int* __restrict__ paths_mm, const int* __restrict__ paths_dd, const int* __restrict__ paths_md,
    const float* __restrict__ pw1l, const float* __restrict__ pw2l,
    float* __restrict__ r, int Nm, int Nd)
{
  const int d = threadIdx.x & 127;
  const int nsub = threadIdx.x >> 7;
  const int g = blockIdx.x * 2 + nsub;
  const int Nt = Nm + Nd;
  if (g >= 2 * Nt) return;
  float acc;
  if (g < Nm)
    acc = gath<LMM, PP>(state, paths_mm, pw1l, g, Nm, d);
  else if (g < Nt)
    acc = gath<LMM, PP>(state + (size_t)Nm * 128, paths_dd, pw1l, g - Nm, Nd, d);
  else
    acc = gath<LMD, PP>(state + (size_t)Nt * 128, paths_md, pw2l, g - Nt, Nt, d);
  r[(size_t)g * 128 + d] = acc * (1.0f / (float)PP);
}

// runtime fallback
__global__ __launch_bounds__(256) void gather_einsum_rt(
    const __hip_bfloat16* __restrict__ feats, const int* __restrict__ paths,
    const float* __restrict__ pw, float* __restrict__ r, int N, int P, int L)
{
  const int d = threadIdx.x & 127;
  const int n = blockIdx.x * 2 + (threadIdx.x >> 7);
  if (n >= N) return;
  float acc = 0.f;
  for (int p = 0; p < P; ++p) {
    const int* ip = paths + ((size_t)p * N + n) * L;
    for (int l = 0; l < L; ++l)
      acc = fmaf(pw[l * 128 + d], __bfloat162float(feats[(size_t)ip[l] * 128 + d]), acc);
  }
  r[(size_t)n * 128 + d] = acc * (1.0f / (float)P);
}

// ---------------- fc layer: K=128, writes state as bf16 ----------------
template<int TR>
__global__ __launch_bounds__(256) void fc_all(
    const float* __restrict__ Rm, const float* __restrict__ W,
    const float* __restrict__ initb, __hip_bfloat16* __restrict__ state, int Ntot, int Nt)
{
  const int col = threadIdx.x & 127;
  const int rh  = __builtin_amdgcn_readfirstlane((int)(threadIdx.x >> 7));
  const int row0 = blockIdx.x * (2 * TR) + rh * TR;
  const float* arow[TR];
#pragma unroll
  for (int r = 0; r < TR; ++r) {
    int rr = row0 + r; if (rr > Ntot - 1) rr = Ntot - 1;
    arow[r] = Rm + (size_t)rr * 128;
  }
  float acc[TR];
#pragma unroll
  for (int r = 0; r < TR; ++r) acc[r] = 0.f;
#pragma unroll 4
  for (int k = 0; k < 128; k += 8) {
    float w[8];
#pragma unroll
    for (int kk = 0; kk < 8; ++kk) w[kk] = W[(size_t)(k + kk) * 128 + col];
#pragma unroll
    for (int r = 0; r < TR; ++r) {
      const float* ap = arow[r] + k;
#pragma unroll
      for (int kk = 0; kk < 8; ++kk) acc[r] = fmaf(ap[kk], w[kk], acc[r]);
    }
  }
#pragma unroll
  for (int r = 0; r < TR; ++r) {
    int rr = row0 + r;
    if (rr < Ntot) {
      int rbase = (rr < Nt) ? rr : rr - Nt;
      float v = ALPHA_ * initb[(size_t)rbase * 128 + col] + (1.f - ALPHA_) * fmaxf(acc[r], 0.f);
      state[(size_t)rr * 128 + col] = __float2bfloat16(v);
    }
  }
}

// MLP collapse (ILP-4)
__global__ void collapse1(const float* __restrict__ W0, const float* __restrict__ b0,
                          const float* __restrict__ W1, const float* __restrict__ b1,
                          float* __restrict__ w01, float* __restrict__ b01,
                          int E, int K0, int H1)
{
  int row = blockIdx.x; int c = threadIdx.x;
  if (c >= H1) return;
  const float* src; float base;
  if (row < E) { src = W0 + (size_t)row * K0; base = 0.f; }
  else         { src = b0; base = b1[c]; }
  float a0 = 0.f, a1 = 0.f, a2 = 0.f, a3 = 0.f;
#pragma unroll 4
  for (int k = 0; k < K0; k += 4) {
    a0 = fmaf(src[k + 0], W1[(size_t)(k + 0) * H1 + c], a0);
    a1 = fmaf(src[k + 1], W1[(size_t)(k + 1) * H1 + c], a1);
    a2 = fmaf(src[k + 2], W1[(size_t)(k + 2) * H1 + c], a2);
    a3 = fmaf(src[k + 3], W1[(size_t)(k + 3) * H1 + c], a3);
  }
  float acc = base + ((a0 + a1) + (a2 + a3));
  if (row < E) w01[(size_t)row * H1 + c] = acc; else b01[c] = acc;
}

__global__ void collapse2(const float* __restrict__ w01, const float* __restrict__ b01,
                          const float* __restrict__ W2, const float* __restrict__ b2,
                          float* __restrict__ w512, float* __restrict__ csc,
                          int E, int H1)
{
  int i = blockIdx.x * blockDim.x + threadIdx.x;
  if (i < E) {
    float a0 = 0.f, a1 = 0.f, a2 = 0.f, a3 = 0.f;
    for (int j = 0; j < H1; j += 4) {
      a0 = fmaf(w01[(size_t)i * H1 + j + 0], W2[j + 0], a0);
      a1 = fmaf(w01[(size_t)i * H1 + j + 1], W2[j + 1], a1);
      a2 = fmaf(w01[(size_t)i * H1 + j + 2], W2[j + 2], a2);
      a3 = fmaf(w01[(size_t)i * H1 + j + 3], W2[j + 3], a3);
    }
    w512[i] = (a0 + a1) + (a2 + a3);
  } else if (i == E) {
    float a = b2[0];
    for (int j = 0; j < H1; ++j) a = fmaf(b01[j], W2[j], a);
    csc[0] = a;
  }
}

__global__ __launch_bounds__(256) void node_partial(
    const __hip_bfloat16* __restrict__ Fmm, const __hip_bfloat16* __restrict__ Fdd,
    const __hip_bfloat16* __restrict__ Fmd,
    const float* __restrict__ w512, float* __restrict__ uv, int Nm, int Nt)
{
  int gid = blockIdx.x * blockDim.x + threadIdx.x;
  int wid = gid >> 6;
  int lane = threadIdx.x & 63;
  if (wid >= Nt) return;
  bool isM = wid < Nm;
  const __hip_bfloat16* X = isM ? (Fmm + (size_t)wid * 128) : (Fdd + (size_t)(wid - Nm) * 128);
  const __hip_bfloat16* Y = Fmd + (size_t)wid * 128;
  const float* w1 = w512 + (isM ? 0 : 256);
  const float* w2 = w1 + 128;
  float s = __bfloat162float(X[lane]) * w1[lane];
  s = fmaf(__bfloat162float(X[lane + 64]), w1[lane + 64], s);
  s = fmaf(__bfloat162float(Y[lane]), w2[lane], s);
  s = fmaf(__bfloat162float(Y[lane + 64]), w2[lane + 64], s);
#pragma unroll
  for (int off = 32; off > 0; off >>= 1) s += __shfl_down(s, off);
  if (lane == 0) uv[wid] = s;
}

__global__ __launch_bounds__(256) void score_kernel(
    const int* __restrict__ samples, const float* __restrict__ u, const float* __restrict__ v,
    const float* __restrict__ csc, float* __restrict__ out, int S)
{
  int s = blockIdx.x * blockDim.x + threadIdx.x;
  if (s >= S) return;
  const int2 ij = ((const int2*)samples)[s];
  float x = u[ij.x] + v[ij.y] + csc[0];
  out[s] = 1.0f / (1.0f + expf(-x));
}

extern "C" void kernel_launch(void* const* d_in, const int* in_sizes, int n_in,
                              void* d_out, int out_size, void* d_ws, size_t ws_size,
                              hipStream_t stream)
{
  const int*   paths_mm = (const int*)d_in[0];
  const int*   paths_dd = (const int*)d_in[1];
  const int*   paths_md = (const int*)d_in[2];
  const float* miRNA    = (const float*)d_in[3];
  const float* disease  = (const float*)d_in[4];
  const int*   samples  = (const int*)d_in[5];
  const float* Wm  = (const float*)d_in[6];
  const float* Wd  = (const float*)d_in[7];
  const float* pw1 = (const float*)d_in[8];
  const float* pw2 = (const float*)d_in[9];
  const float* fcW = (const float*)d_in[10];
  const float* W0  = (const float*)d_in[11];
  const float* b0  = (const float*)d_in[12];
  const float* W1  = (const float*)d_in[13];
  const float* b1  = (const float*)d_in[14];
  const float* W2  = (const float*)d_in[15];
  const float* b2  = (const float*)d_in[16];

  const int D  = 128;
  const int Nm = in_sizes[6] / D;
  const int Nd = in_sizes[7] / D;
  const int Nt = Nm + Nd;
  const int S  = in_sizes[5] / 2;
  const int layers = in_sizes[10] / (D * D);
  const int L1 = in_sizes[8] / (layers * D);
  const int L2 = in_sizes[9] / (layers * D);
  const int P  = in_sizes[0] / (Nm * L1);
  const int E  = 4 * D;
  const int K0 = in_sizes[12];
  const int H1 = in_sizes[14];
  const int Kpm = cdiv(Nm, 128) * 128;   // 8064
  const int Kpd = cdiv(Nd, 128) * 128;   // 6016
  const size_t NtD = (size_t)Nt * D;

  float* out = (float*)d_out;
  float* ws  = (float*)d_ws;
  size_t off = 0;
  float* init  = ws + off; off += NtD;                       // f32 summed init
  __hip_bfloat16* state = (__hip_bfloat16*)(ws + off); off += NtD;  // 2*NtD bf16
  float* bufR  = ws + off; off += 2 * NtD;                   // gather output (f32)
  float* w01   = ws + off; off += (size_t)E * H1;
  float* b01   = ws + off; off += H1;
  float* w512  = ws + off; off += E;
  float* csc   = ws + off; off += 1;
  float* uv    = ws + off; off += Nt;
  __hip_bfloat16* WtTm = (__hip_bfloat16*)(ws + off); off += (size_t)D * Kpm / 2;
  __hip_bfloat16* WtTd = (__hip_bfloat16*)(ws + off); off += (size_t)D * Kpd / 2;
  float* pextra = ws + off;
  const bool big_ws = (off + NtD) * 4 <= ws_size;
  (void)n_in; (void)out_size;

  // 1. tile-major bf16 weight transposes
  make_wtT<<<Kpm / 32, 256, 0, stream>>>(Wm, WtTm, Nm);
  make_wtT<<<Kpd / 32, 256, 0, stream>>>(Wd, WtTd, Nd);

  // 2. MLP collapse
  collapse1<<<E + 1, 64, 0, stream>>>(W0, b0, W1, b1, w01, b01, E, K0, H1);
  collapse2<<<cdiv(E + 1, 256), 256, 0, stream>>>(w01, b01, W2, b2, w512, csc, E, H1);

  // 3. init GEMMs (no-LDS direct-reg MFMA, BM=32, BK=128)
  {
    int nbm = cdiv(Nm, 32), nbd = cdiv(Nd, 32);
    int n4 = (int)(NtD / 4);
    P8 parr;
    parr.p[0] = init;
    parr.p[1] = bufR;
    parr.p[2] = bufR + NtD;
    if (big_ws) {
      parr.p[3] = pextra;
      init_mfma3<4><<<(nbm + nbd) * 4, 256, 0, stream>>>(
          miRNA, WtTm, Nm, nbm, Kpm, disease, WtTd, Nd, Kpd, parr);
      combineN<4><<<cdiv(n4, 256), 256, 0, stream>>>(parr, (float4v*)init, state, n4, (int)NtD);
    } else {
      init_mfma3<3><<<(nbm + nbd) * 3, 256, 0, stream>>>(
          miRNA, WtTm, Nm, nbm, Kpm, disease, WtTd, Nd, Kpd, parr);
      combineN<3><<<cdiv(n4, 256), 256, 0, stream>>>(parr, (float4v*)init, state, n4, (int)NtD);
    }
  }

  // 4. fused path-layer chains (state bf16, residual from f32 init)
  constexpr int TR = 8;
  for (int l = 0; l < layers; ++l) {
    const float* pw1l = pw1 + (size_t)l * L1 * D;
    const float* pw2l = pw2 + (size_t)l * L2 * D;
    if (L1 == 4 && L2 == 6 && P == 8) {
      gather_all<4, 6, 8><<<Nt, 256, 0, stream>>>(
          state, paths_mm, paths_dd, paths_md, pw1l, pw2l, bufR, Nm, Nd);
    } else {
      gather_einsum_rt<<<cdiv(Nm, 2), 256, 0, stream>>>(state, paths_mm, pw1l, bufR, Nm, P, L1);
      gather_einsum_rt<<<cdiv(Nd, 2), 256, 0, stream>>>(state + (size_t)Nm * D, paths_dd, pw1l,
                                                        bufR + (size_t)Nm * D, Nd, P, L1);
      gather_einsum_rt<<<cdiv(Nt, 2), 256, 0, stream>>>(state + NtD, paths_md, pw2l,
                                                        bufR + NtD, Nt, P, L2);
    }
    fc_all<TR><<<cdiv(2 * Nt, 2 * TR), 256, 0, stream>>>(
        bufR, fcW + (size_t)l * D * D, init, state, 2 * Nt, Nt);
  }

  // 5. per-node partial dots + scoring
  node_partial<<<cdiv(Nt * 64, 256), 256, 0, stream>>>(
      state, state + (size_t)Nm * D, state + NtD, w512, uv, Nm, Nt);
  score_kernel<<<cdiv(S, 256), 256, 0, stream>>>(samples, uv, uv + Nm, csc, out, S);
}

// Round 9
// 379.204 us; speedup vs baseline: 1.1560x; 1.1560x over previous
//
#include <hip/hip_runtime.h>
#include <hip/hip_bf16.h>
#include <cstdint>
#include <cstddef>

#define ALPHA_ 0.1f

static inline int cdiv(int a, int b) { return (a + b - 1) / b; }

typedef __attribute__((ext_vector_type(8))) short short8;
typedef __attribute__((ext_vector_type(4))) short short4v;
typedef __attribute__((ext_vector_type(4))) float float4v;

struct P8 { float* p[8]; };

__device__ __forceinline__ void gload_lds16(const void* g, void* l) {
  __builtin_amdgcn_global_load_lds((const __attribute__((address_space(1))) unsigned int*)g,
                                   (__attribute__((address_space(3))) unsigned int*)l,
                                   16, 0, 0);
}

// ---------------- WtT builder: per-32k-tile [kg][col][e] bf16 layout of W (K x 128) -------
// tile = k/32, kg = (k%32)/8, e = k%8: element (k,c) -> WtT[tile*4096 + kg*1024 + c*8 + e].
// This makes both the glds source AND dest linear, and ds_read conflict-free (2-way max).
__global__ __launch_bounds__(256) void make_wtT(const float* __restrict__ W,
                                                __hip_bfloat16* __restrict__ WtT,
                                                int K)
{
  __shared__ float tile[32][129];
  const int t  = threadIdx.x;
  const int s  = blockIdx.x;
  const int k0 = s * 32;
#pragma unroll
  for (int pass = 0; pass < 4; ++pass) {
    int idx = pass * 1024 + t * 4;           // 4096 floats, 4 per thread per pass
    int k = idx >> 7, c = idx & 127;
    float4v v;
    const float* src = W + (size_t)(k0 + k) * 128 + c;
    if (k0 + k < K) v = *(const float4v*)src;
    else            v = (float4v){0.f, 0.f, 0.f, 0.f};
    tile[k][c] = v.x; tile[k][c + 1] = v.y; tile[k][c + 2] = v.z; tile[k][c + 3] = v.w;
  }
  __syncthreads();
#pragma unroll
  for (int pass = 0; pass < 16; ++pass) {
    int idx = pass * 256 + t;                // dest-linear
    int kg = idx >> 10, rem = idx & 1023;
    int c = rem >> 3, e = rem & 7;
    WtT[(size_t)s * 4096 + idx] = __float2bfloat16(tile[kg * 8 + e][c]);
  }
}

// ---------------- init GEMM: BK=256 (1KB/row DRAM visits), 2-phase LDS, 1 block/CU --------
// 512 thr = 8 waves; tile 128 rows x 128 cols. Per step: A[128][256]f32 -> bf16 LDS (swizzled),
// W 8x8KB subtiles via linear glds. Then 8 subs x 8 MFMA per wave. KSPLIT partials.
template<int KSPLIT>
__global__ __launch_bounds__(512) void init_mfma4(
    const float* __restrict__ Am, const __hip_bfloat16* __restrict__ Wtm, int Nm_, int nbm, int Kpm,
    const float* __restrict__ Ad, const __hip_bfloat16* __restrict__ Wtd, int Nd_, int Kpd,
    P8 parr)
{
  __shared__ __align__(16) __hip_bfloat16 lds_a[128 * 256];   // 64KB
  __shared__ __align__(16) __hip_bfloat16 lds_w[8 * 4096];    // 64KB (8 subtiles)

  const int t    = threadIdx.x;
  const int lane = t & 63;
  const int wv   = t >> 6;

  const int chunk = blockIdx.x % KSPLIT;
  int mb          = blockIdx.x / KSPLIT;

  const float* A; const __hip_bfloat16* Wt; int N, K, Kpad, rowoff, rb;
  if (mb < nbm) { A = Am; Wt = Wtm; N = Nm_; K = Nm_; Kpad = Kpm; rowoff = 0;   rb = mb; }
  else          { A = Ad; Wt = Wtd; N = Nd_; K = Nd_; Kpad = Kpd; rowoff = Nm_; rb = mb - nbm; }

  float* Cp = parr.p[chunk];

  const int St = Kpad / 256;
  const int s0 = (int)(((long)St * chunk) / KSPLIT);
  const int s1 = (int)(((long)St * (chunk + 1)) / KSPLIT);

  // ---- A staging map: thread t loads 256B contiguous: row t>>2, float-quarter (t&3)*64 ----
  const int strow = t >> 2;              // 0..127
  const int stq   = t & 3;               // 0..3
  const int row_g0 = rb * 128;
  int ra_st = row_g0 + strow; if (ra_st > N - 1) ra_st = N - 1;
  const float* stbase = A + (size_t)ra_st * K;
  const int kclamp = K - 4;

  // ---- compute-side ids (identical mapping to validated R5/R7 kernels) ----
  const int rloc  = lane & 15;
  const int kg    = lane >> 4;           // 0..3
  const int row_l = wv * 16 + rloc;      // 0..127
  const int row   = row_g0 + row_l;

  float4v acc[8];
#pragma unroll
  for (int mt = 0; mt < 8; ++mt) acc[mt] = (float4v){0.f, 0.f, 0.f, 0.f};

  const char* wt_bytes = (const char*)Wt;

  for (int s = s0; s < s1; ++s) {
    // ---- issue W subtile DMAs (linear src, linear dest) ----
#pragma unroll
    for (int sub = 0; sub < 8; ++sub) {
      gload_lds16(wt_bytes + (size_t)(s * 8 + sub) * 8192 + (size_t)(wv * 64 + lane) * 16,
                  &lds_w[sub * 4096 + wv * 512]);
    }
    // ---- A: 16x float4 contiguous per thread ----
    float4v av[16];
#pragma unroll
    for (int i = 0; i < 16; ++i) {
      int kb = s * 256 + stq * 64 + i * 4;
      if (kb > kclamp) kb = kclamp;
      av[i] = *(const float4v*)(stbase + kb);
    }
    // ---- cvt + swizzled LDS write: chunk c holds 8 bf16 (16B) ----
#pragma unroll
    for (int c = 0; c < 8; ++c) {
      union { short8 v; __hip_bfloat16 h[8]; } pk;
      pk.h[0] = __float2bfloat16(av[2 * c].x);     pk.h[1] = __float2bfloat16(av[2 * c].y);
      pk.h[2] = __float2bfloat16(av[2 * c].z);     pk.h[3] = __float2bfloat16(av[2 * c].w);
      pk.h[4] = __float2bfloat16(av[2 * c + 1].x); pk.h[5] = __float2bfloat16(av[2 * c + 1].y);
      pk.h[6] = __float2bfloat16(av[2 * c + 1].z); pk.h[7] = __float2bfloat16(av[2 * c + 1].w);
      int j = stq * 8 + c;                                        // chunk index 0..31
      int slot = (j & 24) | (((j & 7) ^ (strow & 7) ^ (j >> 3)) & 7);
      *(short8*)(lds_a + strow * 256 + slot * 8) = pk.v;
    }
    __syncthreads();

    // ---- compute: 8 subs x 8 MFMA ----
#pragma unroll
    for (int sub = 0; sub < 8; ++sub) {
      int j = sub * 4 + kg;
      int slot = (j & 24) | (((j & 7) ^ (row_l & 7) ^ (j >> 3)) & 7);
      short8 afrag = *(const short8*)(lds_a + row_l * 256 + slot * 8);
      const __hip_bfloat16* lw = lds_w + sub * 4096 + kg * 1024;
#pragma unroll
      for (int mt = 0; mt < 8; ++mt) {
        short8 wfrag = *(const short8*)(lw + (mt * 16 + rloc) * 8);
        acc[mt] = __builtin_amdgcn_mfma_f32_16x16x32_bf16(wfrag, afrag, acc[mt], 0, 0, 0);
      }
    }
    __syncthreads();
  }

  if (row < N) {
    float* dst = Cp + (size_t)(rowoff + row) * 128 + kg * 4;
#pragma unroll
    for (int mt = 0; mt < 8; ++mt)
      *(float4v*)(dst + mt * 16) = acc[mt];
  }
}

// sum NP partials -> init (f32) + both state sections (bf16)
template<int NP>
__global__ __launch_bounds__(256) void combineN(
    P8 parr, float4v* __restrict__ o_init, __hip_bfloat16* __restrict__ state,
    int n4, int NtD)
{
  int i = blockIdx.x * 256 + threadIdx.x;
  if (i >= n4) return;
  float4v s = ((const float4v*)parr.p[0])[i];
#pragma unroll
  for (int j = 1; j < NP; ++j) {
    float4v x = ((const float4v*)parr.p[j])[i];
    s.x += x.x; s.y += x.y; s.z += x.z; s.w += x.w;
  }
  o_init[i] = s;
  union { short4v v; __hip_bfloat16 h[4]; } b;
  b.h[0] = __float2bfloat16(s.x); b.h[1] = __float2bfloat16(s.y);
  b.h[2] = __float2bfloat16(s.z); b.h[3] = __float2bfloat16(s.w);
  *(short4v*)(state + (size_t)i * 4) = b.v;
  *(short4v*)(state + (size_t)NtD + (size_t)i * 4) = b.v;
}

// ---------------- unified gather (state in bf16), unrolled over P and L ----------------
template<int L, int PP>
__device__ __forceinline__ float gath(const __hip_bfloat16* __restrict__ sect,
                                      const int* __restrict__ paths,
                                      const float* __restrict__ pw, int n, int N, int d)
{
  float pwv[L];
#pragma unroll
  for (int l = 0; l < L; ++l) pwv[l] = pw[l * 128 + d];
  float acc = 0.f;
  const int* ip0 = paths + (size_t)n * L;
#pragma unroll
  for (int p = 0; p < PP; ++p) {
    const int* ip = ip0 + (size_t)p * N * L;   // wave-uniform -> scalar loads
    int idx[L];
#pragma unroll
    for (int l = 0; l < L; ++l) idx[l] = ip[l];
#pragma unroll
    for (int l = 0; l < L; ++l)
      acc = fmaf(pwv[l], __bfloat162float(sect[(size_t)idx[l] * 128 + d]), acc);
  }
  return acc;
}

template<int LMM, int LMD, int PP>
__global__ __launch_bounds__(256) void gather_all(
    const __hip_bfloat16* __restrict__ state,
    const int* __restrict__ paths_mm, const int* __restrict__ paths_dd, const int* __restrict__ paths_md,
    const float* __restrict__ pw1l, const float* __restrict__ pw2l,
    float* __restrict__ r, int Nm, int Nd)
{
  const int d = threadIdx.x & 127;
  const int nsub = threadIdx.x >> 7;
  const int g = blockIdx.x * 2 + nsub;
  const int Nt = Nm + Nd;
  if (g >= 2 * Nt) return;
  float acc;
  if (g < Nm)
    acc = gath<LMM, PP>(state, paths_mm, pw1l, g, Nm, d);
  else if (g < Nt)
    acc = gath<LMM, PP>(state + (size_t)Nm * 128, paths_dd, pw1l, g - Nm, Nd, d);
  else
    acc = gath<LMD, PP>(state + (size_t)Nt * 128, paths_md, pw2l, g - Nt, Nt, d);
  r[(size_t)g * 128 + d] = acc * (1.0f / (float)PP);
}

// runtime fallback
__global__ __launch_bounds__(256) void gather_einsum_rt(
    const __hip_bfloat16* __restrict__ feats, const int* __restrict__ paths,
    const float* __restrict__ pw, float* __restrict__ r, int N, int P, int L)
{
  const int d = threadIdx.x & 127;
  const int n = blockIdx.x * 2 + (threadIdx.x >> 7);
  if (n >= N) return;
  float acc = 0.f;
  for (int p = 0; p < P; ++p) {
    const int* ip = paths + ((size_t)p * N + n) * L;
    for (int l = 0; l < L; ++l)
      acc = fmaf(pw[l * 128 + d], __bfloat162float(feats[(size_t)ip[l] * 128 + d]), acc);
  }
  r[(size_t)n * 128 + d] = acc * (1.0f / (float)P);
}

// ---------------- fc layer: K=128, writes state as bf16 ----------------
template<int TR>
__global__ __launch_bounds__(256) void fc_all(
    const float* __restrict__ Rm, const float* __restrict__ W,
    const float* __restrict__ initb, __hip_bfloat16* __restrict__ state, int Ntot, int Nt)
{
  const int col = threadIdx.x & 127;
  const int rh  = __builtin_amdgcn_readfirstlane((int)(threadIdx.x >> 7));
  const int row0 = blockIdx.x * (2 * TR) + rh * TR;
  const float* arow[TR];
#pragma unroll
  for (int r = 0; r < TR; ++r) {
    int rr = row0 + r; if (rr > Ntot - 1) rr = Ntot - 1;
    arow[r] = Rm + (size_t)rr * 128;
  }
  float acc[TR];
#pragma unroll
  for (int r = 0; r < TR; ++r) acc[r] = 0.f;
#pragma unroll 4
  for (int k = 0; k < 128; k += 8) {
    float w[8];
#pragma unroll
    for (int kk = 0; kk < 8; ++kk) w[kk] = W[(size_t)(k + kk) * 128 + col];
#pragma unroll
    for (int r = 0; r < TR; ++r) {
      const float* ap = arow[r] + k;
#pragma unroll
      for (int kk = 0; kk < 8; ++kk) acc[r] = fmaf(ap[kk], w[kk], acc[r]);
    }
  }
#pragma unroll
  for (int r = 0; r < TR; ++r) {
    int rr = row0 + r;
    if (rr < Ntot) {
      int rbase = (rr < Nt) ? rr : rr - Nt;
      float v = ALPHA_ * initb[(size_t)rbase * 128 + col] + (1.f - ALPHA_) * fmaxf(acc[r], 0.f);
      state[(size_t)rr * 128 + col] = __float2bfloat16(v);
    }
  }
}

// MLP collapse (ILP-4)
__global__ void collapse1(const float* __restrict__ W0, const float* __restrict__ b0,
                          const float* __restrict__ W1, const float* __restrict__ b1,
                          float* __restrict__ w01, float* __restrict__ b01,
                          int E, int K0, int H1)
{
  int row = blockIdx.x; int c = threadIdx.x;
  if (c >= H1) return;
  const float* src; float base;
  if (row < E) { src = W0 + (size_t)row * K0; base = 0.f; }
  else         { src = b0; base = b1[c]; }
  float a0 = 0.f, a1 = 0.f, a2 = 0.f, a3 = 0.f;
#pragma unroll 4
  for (int k = 0; k < K0; k += 4) {
    a0 = fmaf(src[k + 0], W1[(size_t)(k + 0) * H1 + c], a0);
    a1 = fmaf(src[k + 1], W1[(size_t)(k + 1) * H1 + c], a1);
    a2 = fmaf(src[k + 2], W1[(size_t)(k + 2) * H1 + c], a2);
    a3 = fmaf(src[k + 3], W1[(size_t)(k + 3) * H1 + c], a3);
  }
  float acc = base + ((a0 + a1) + (a2 + a3));
  if (row < E) w01[(size_t)row * H1 + c] = acc; else b01[c] = acc;
}

__global__ void collapse2(const float* __restrict__ w01, const float* __restrict__ b01,
                          const float* __restrict__ W2, const float* __restrict__ b2,
                          float* __restrict__ w512, float* __restrict__ csc,
                          int E, int H1)
{
  int i = blockIdx.x * blockDim.x + threadIdx.x;
  if (i < E) {
    float a0 = 0.f, a1 = 0.f, a2 = 0.f, a3 = 0.f;
    for (int j = 0; j < H1; j += 4) {
      a0 = fmaf(w01[(size_t)i * H1 + j + 0], W2[j + 0], a0);
      a1 = fmaf(w01[(size_t)i * H1 + j + 1], W2[j + 1], a1);
      a2 = fmaf(w01[(size_t)i * H1 + j + 2], W2[j + 2], a2);
      a3 = fmaf(w01[(size_t)i * H1 + j + 3], W2[j + 3], a3);
    }
    w512[i] = (a0 + a1) + (a2 + a3);
  } else if (i == E) {
    float a = b2[0];
    for (int j = 0; j < H1; ++j) a = fmaf(b01[j], W2[j], a);
    csc[0] = a;
  }
}

__global__ __launch_bounds__(256) void node_partial(
    const __hip_bfloat16* __restrict__ Fmm, const __hip_bfloat16* __restrict__ Fdd,
    const __hip_bfloat16* __restrict__ Fmd,
    const float* __restrict__ w512, float* __restrict__ uv, int Nm, int Nt)
{
  int gid = blockIdx.x * blockDim.x + threadIdx.x;
  int wid = gid >> 6;
  int lane = threadIdx.x & 63;
  if (wid >= Nt) return;
  bool isM = wid < Nm;
  const __hip_bfloat16* X = isM ? (Fmm + (size_t)wid * 128) : (Fdd + (size_t)(wid - Nm) * 128);
  const __hip_bfloat16* Y = Fmd + (size_t)wid * 128;
  const float* w1 = w512 + (isM ? 0 : 256);
  const float* w2 = w1 + 128;
  float s = __bfloat162float(X[lane]) * w1[lane];
  s = fmaf(__bfloat162float(X[lane + 64]), w1[lane + 64], s);
  s = fmaf(__bfloat162float(Y[lane]), w2[lane], s);
  s = fmaf(__bfloat162float(Y[lane + 64]), w2[lane + 64], s);
#pragma unroll
  for (int off = 32; off > 0; off >>= 1) s += __shfl_down(s, off);
  if (lane == 0) uv[wid] = s;
}

__global__ __launch_bounds__(256) void score_kernel(
    const int* __restrict__ samples, const float* __restrict__ u, const float* __restrict__ v,
    const float* __restrict__ csc, float* __restrict__ out, int S)
{
  int s = blockIdx.x * blockDim.x + threadIdx.x;
  if (s >= S) return;
  const int2 ij = ((const int2*)samples)[s];
  float x = u[ij.x] + v[ij.y] + csc[0];
  out[s] = 1.0f / (1.0f + expf(-x));
}

extern "C" void kernel_launch(void* const* d_in, const int* in_sizes, int n_in,
                              void* d_out, int out_size, void* d_ws, size_t ws_size,
                              hipStream_t stream)
{
  const int*   paths_mm = (const int*)d_in[0];
  const int*   paths_dd = (const int*)d_in[1];
  const int*   paths_md = (const int*)d_in[2];
  const float* miRNA    = (const float*)d_in[3];
  const float* disease  = (const float*)d_in[4];
  const int*   samples  = (const int*)d_in[5];
  const float* Wm  = (const float*)d_in[6];
  const float* Wd  = (const float*)d_in[7];
  const float* pw1 = (const float*)d_in[8];
  const float* pw2 = (const float*)d_in[9];
  const float* fcW = (const float*)d_in[10];
  const float* W0  = (const float*)d_in[11];
  const float* b0  = (const float*)d_in[12];
  const float* W1  = (const float*)d_in[13];
  const float* b1  = (const float*)d_in[14];
  const float* W2  = (const float*)d_in[15];
  const float* b2  = (const float*)d_in[16];

  const int D  = 128;
  const int Nm = in_sizes[6] / D;
  const int Nd = in_sizes[7] / D;
  const int Nt = Nm + Nd;
  const int S  = in_sizes[5] / 2;
  const int layers = in_sizes[10] / (D * D);
  const int L1 = in_sizes[8] / (layers * D);
  const int L2 = in_sizes[9] / (layers * D);
  const int P  = in_sizes[0] / (Nm * L1);
  const int E  = 4 * D;
  const int K0 = in_sizes[12];
  const int H1 = in_sizes[14];
  const int Kpm = cdiv(Nm, 256) * 256;   // 8192
  const int Kpd = cdiv(Nd, 256) * 256;   // 6144
  const size_t NtD = (size_t)Nt * D;

  float* out = (float*)d_out;
  float* ws  = (float*)d_ws;
  size_t off = 0;
  float* init  = ws + off; off += NtD;                       // f32 summed init
  __hip_bfloat16* state = (__hip_bfloat16*)(ws + off); off += NtD;  // 2*NtD bf16
  float* bufR  = ws + off; off += 2 * NtD;                   // gather output (f32)
  float* w01   = ws + off; off += (size_t)E * H1;
  float* b01   = ws + off; off += H1;
  float* w512  = ws + off; off += E;
  float* csc   = ws + off; off += 1;
  float* uv    = ws + off; off += Nt;
  __hip_bfloat16* WtTm = (__hip_bfloat16*)(ws + off); off += (size_t)D * Kpm / 2;
  __hip_bfloat16* WtTd = (__hip_bfloat16*)(ws + off); off += (size_t)D * Kpd / 2;
  float* pextra = ws + off;
  const bool big_ws = (off + 4 * NtD) * 4 <= ws_size;
  (void)n_in; (void)out_size;

  // 1. tile-major bf16 weight transposes
  make_wtT<<<Kpm / 32, 256, 0, stream>>>(Wm, WtTm, Nm);
  make_wtT<<<Kpd / 32, 256, 0, stream>>>(Wd, WtTd, Nd);

  // 2. MLP collapse
  collapse1<<<E + 1, 64, 0, stream>>>(W0, b0, W1, b1, w01, b01, E, K0, H1);
  collapse2<<<cdiv(E + 1, 256), 256, 0, stream>>>(w01, b01, W2, b2, w512, csc, E, H1);

  // 3. init GEMMs (BK=256 wide-visit 2-phase LDS MFMA)
  {
    int nbm = cdiv(Nm, 128), nbd = cdiv(Nd, 128);
    int n4 = (int)(NtD / 4);
    P8 parr;
    parr.p[0] = init;
    parr.p[1] = bufR;
    parr.p[2] = bufR + NtD;
    if (big_ws) {
      for (int j = 0; j < 4; ++j) parr.p[3 + j] = pextra + (size_t)j * NtD;
      init_mfma4<7><<<(nbm + nbd) * 7, 512, 0, stream>>>(
          miRNA, WtTm, Nm, nbm, Kpm, disease, WtTd, Nd, Kpd, parr);
      combineN<7><<<cdiv(n4, 256), 256, 0, stream>>>(parr, (float4v*)init, state, n4, (int)NtD);
    } else {
      init_mfma4<3><<<(nbm + nbd) * 3, 512, 0, stream>>>(
          miRNA, WtTm, Nm, nbm, Kpm, disease, WtTd, Nd, Kpd, parr);
      combineN<3><<<cdiv(n4, 256), 256, 0, stream>>>(parr, (float4v*)init, state, n4, (int)NtD);
    }
  }

  // 4. fused path-layer chains (state bf16, residual from f32 init)
  constexpr int TR = 8;
  for (int l = 0; l < layers; ++l) {
    const float* pw1l = pw1 + (size_t)l * L1 * D;
    const float* pw2l = pw2 + (size_t)l * L2 * D;
    if (L1 == 4 && L2 == 6 && P == 8) {
      gather_all<4, 6, 8><<<Nt, 256, 0, stream>>>(
          state, paths_mm, paths_dd, paths_md, pw1l, pw2l, bufR, Nm, Nd);
    } else {
      gather_einsum_rt<<<cdiv(Nm, 2), 256, 0, stream>>>(state, paths_mm, pw1l, bufR, Nm, P, L1);
      gather_einsum_rt<<<cdiv(Nd, 2), 256, 0, stream>>>(state + (size_t)Nm * D, paths_dd, pw1l,
                                                        bufR + (size_t)Nm * D, Nd, P, L1);
      gather_einsum_rt<<<cdiv(Nt, 2), 256, 0, stream>>>(state + NtD, paths_md, pw2l,
                                                        bufR + NtD, Nt, P, L2);
    }
    fc_all<TR><<<cdiv(2 * Nt, 2 * TR), 256, 0, stream>>>(
        bufR, fcW + (size_t)l * D * D, init, state, 2 * Nt, Nt);
  }

  // 5. per-node partial dots + scoring
  node_partial<<<cdiv(Nt * 64, 256), 256, 0, stream>>>(
      state, state + (size_t)Nm * D, state + NtD, w512, uv, Nm, Nt);
  score_kernel<<<cdiv(S, 256), 256, 0, stream>>>(samples, uv, uv + Nm, csc, out, S);
}

// Round 10
// 340.152 us; speedup vs baseline: 1.2888x; 1.1148x over previous
//
#include <hip/hip_runtime.h>
#include <hip/hip_bf16.h>
#include <cstdint>
#include <cstddef>

#define ALPHA_ 0.1f

static inline int cdiv(int a, int b) { return (a + b - 1) / b; }

typedef __attribute__((ext_vector_type(8))) short short8;
typedef __attribute__((ext_vector_type(4))) short short4v;
typedef __attribute__((ext_vector_type(2))) short short2v;
typedef __attribute__((ext_vector_type(4))) float float4v;

struct P8 { float* p[8]; };

__device__ __forceinline__ void gload_lds16(const void* g, void* l) {
  __builtin_amdgcn_global_load_lds((const __attribute__((address_space(1))) unsigned int*)g,
                                   (__attribute__((address_space(3))) unsigned int*)l,
                                   16, 0, 0);
}

// ---------------- WtT builder: per-32k-tile [kg][col][e] bf16 layout of W (K x 128) -------
// tile = k/32, kg = (k%32)/8, e = k%8: element (k,c) -> WtT[tile*4096 + kg*1024 + c*8 + e].
__global__ __launch_bounds__(256) void make_wtT(const float* __restrict__ W,
                                                __hip_bfloat16* __restrict__ WtT,
                                                int K)
{
  __shared__ float tile[32][129];
  const int t  = threadIdx.x;
  const int s  = blockIdx.x;
  const int k0 = s * 32;
#pragma unroll
  for (int pass = 0; pass < 4; ++pass) {
    int idx = pass * 1024 + t * 4;
    int k = idx >> 7, c = idx & 127;
    float4v v;
    const float* src = W + (size_t)(k0 + k) * 128 + c;
    if (k0 + k < K) v = *(const float4v*)src;
    else            v = (float4v){0.f, 0.f, 0.f, 0.f};
    tile[k][c] = v.x; tile[k][c + 1] = v.y; tile[k][c + 2] = v.z; tile[k][c + 3] = v.w;
  }
  __syncthreads();
#pragma unroll
  for (int pass = 0; pass < 16; ++pass) {
    int idx = pass * 256 + t;
    int kg = idx >> 10, rem = idx & 1023;
    int c = rem >> 3, e = rem & 7;
    WtT[(size_t)s * 4096 + idx] = __float2bfloat16(tile[kg * 8 + e][c]);
  }
}

// ---------------- init GEMM: copy-like A staging (512B wave-runs), BM=128, BK=128 --------
// 512 thr = 8 waves, 64KB LDS, 2 blocks/CU. A: flat f = pass*512+t -> consecutive lanes =
// consecutive addresses (512B contiguous per wave-instr). LDS A swizzle c' = c ^ (row&15).
// W: linear global_load_lds from [kg][col][e] WtT subtiles.
template<int KSPLIT>
__global__ __launch_bounds__(512) void init_mfma5(
    const float* __restrict__ Am, const __hip_bfloat16* __restrict__ Wtm, int Nm_, int nbm,
    const float* __restrict__ Ad, const __hip_bfloat16* __restrict__ Wtd, int Nd_, int Kpd,
    P8 parr)
{
  __shared__ __align__(16) __hip_bfloat16 lds_a[128 * 128];   // 32KB
  __shared__ __align__(16) __hip_bfloat16 lds_w[4 * 4096];    // 32KB (4 subtiles of 32k)

  const int t    = threadIdx.x;
  const int lane = t & 63;
  const int wv   = t >> 6;

  const int chunk = blockIdx.x % KSPLIT;
  int mb          = blockIdx.x / KSPLIT;

  const float* A; const __hip_bfloat16* Wt; int N, K, Kpad, rowoff, rb;
  if (mb < nbm) { A = Am; Wt = Wtm; N = Nm_; K = Nm_; Kpad = nbm * 128; rowoff = 0;   rb = mb; }
  else          { A = Ad; Wt = Wtd; N = Nd_; K = Nd_; Kpad = Kpd;       rowoff = Nm_; rb = mb - nbm; }

  float* Cp = parr.p[chunk];

  const int St = Kpad / 128;
  const int s0 = (int)(((long)St * chunk) / KSPLIT);
  const int s1 = (int)(((long)St * (chunk + 1)) / KSPLIT);

  const int row_g0 = rb * 128;
  const int kclamp = K - 4;

  // ---- A staging map: pass p, flat f = p*512 + t (float4 units). row = f>>5, kq = f&31. ----
  const float* apass[8];
  int aw_byte[8];
#pragma unroll
  for (int p = 0; p < 8; ++p) {
    int f   = p * 512 + t;
    int row = f >> 5, kq = f & 31;
    int rg  = row_g0 + row; if (rg > N - 1) rg = N - 1;
    apass[p] = A + (size_t)rg * K + kq * 4;          // + s*128 per step
    int c = kq >> 1, h = kq & 1;
    aw_byte[p] = row * 256 + ((c ^ (row & 15)) << 4) + h * 8;
  }

  // ---- compute-side frag offsets ----
  const int rloc  = lane & 15;
  const int kg    = lane >> 4;            // 0..3
  const int row_l = wv * 16 + rloc;
  int a_rbyte[4];
#pragma unroll
  for (int sub = 0; sub < 4; ++sub) {
    int c = sub * 4 + kg;
    a_rbyte[sub] = row_l * 256 + ((c ^ (row_l & 15)) << 4);
  }
  int w_roff[8];
#pragma unroll
  for (int mt = 0; mt < 8; ++mt)
    w_roff[mt] = (mt * 16 + rloc) * 8;    // element offset within [kg] plane

  float4v acc[8];
#pragma unroll
  for (int mt = 0; mt < 8; ++mt) acc[mt] = (float4v){0.f, 0.f, 0.f, 0.f};

  const char* wt_bytes = (const char*)Wt;

  for (int s = s0; s < s1; ++s) {
    // ---- W: 4 linear glds (32KB total) ----
#pragma unroll
    for (int i = 0; i < 4; ++i) {
      gload_lds16(wt_bytes + (size_t)(s * 4) * 8192 + (size_t)(i * 512 + wv * 64 + lane) * 16,
                  (char*)lds_w + (size_t)(i * 512 + wv * 64) * 16);
    }
    // ---- A: 8 copy-like loads ----
    float4v av[8];
    const int kb = s * 128;
#pragma unroll
    for (int p = 0; p < 8; ++p) {
      int ko = kb; if (ko > kclamp - 0) ko = ko; // kb itself; clamp applied per-pass below
      int off = kb;  (void)ko;
      // clamp: apass already includes kq*4; max kq*4 = 124, so kb + 124 + 4 may exceed K
      const float* src = apass[p] + kb;
      // per-lane clamp (rare, tail tiles only)
      ptrdiff_t rel = (src - A);   // element index
      av[p] = *(const float4v*)(A + ((rel > (ptrdiff_t)( (size_t)(N) * K - 4)) ? ((size_t)N * K - 4) : rel));
    }
    // ---- cvt + swizzled LDS write (8B each) ----
#pragma unroll
    for (int p = 0; p < 8; ++p) {
      union { short4v v; __hip_bfloat16 h[4]; } pk;
      pk.h[0] = __float2bfloat16(av[p].x); pk.h[1] = __float2bfloat16(av[p].y);
      pk.h[2] = __float2bfloat16(av[p].z); pk.h[3] = __float2bfloat16(av[p].w);
      *(short4v*)((char*)lds_a + aw_byte[p]) = pk.v;
    }
    __syncthreads();

    // ---- compute: 4 subs x 8 MFMA ----
#pragma unroll
    for (int sub = 0; sub < 4; ++sub) {
      short8 afrag = *(const short8*)((const char*)lds_a + a_rbyte[sub]);
      const __hip_bfloat16* lw = lds_w + sub * 4096 + kg * 1024;
#pragma unroll
      for (int mt = 0; mt < 8; ++mt) {
        short8 wfrag = *(const short8*)(lw + w_roff[mt]);
        acc[mt] = __builtin_amdgcn_mfma_f32_16x16x32_bf16(wfrag, afrag, acc[mt], 0, 0, 0);
      }
    }
    __syncthreads();
  }

  int row = row_g0 + row_l;
  if (row < N) {
    float* dst = Cp + (size_t)(rowoff + row) * 128 + kg * 4;
#pragma unroll
    for (int mt = 0; mt < 8; ++mt)
      *(float4v*)(dst + mt * 16) = acc[mt];
  }
}

// sum NP partials -> init (f32) + both state sections (bf16)
template<int NP>
__global__ __launch_bounds__(256) void combineN(
    P8 parr, float4v* __restrict__ o_init, __hip_bfloat16* __restrict__ state,
    int n4, int NtD)
{
  int i = blockIdx.x * 256 + threadIdx.x;
  if (i >= n4) return;
  float4v s = ((const float4v*)parr.p[0])[i];
#pragma unroll
  for (int j = 1; j < NP; ++j) {
    float4v x = ((const float4v*)parr.p[j])[i];
    s.x += x.x; s.y += x.y; s.z += x.z; s.w += x.w;
  }
  o_init[i] = s;
  union { short4v v; __hip_bfloat16 h[4]; } b;
  b.h[0] = __float2bfloat16(s.x); b.h[1] = __float2bfloat16(s.y);
  b.h[2] = __float2bfloat16(s.z); b.h[3] = __float2bfloat16(s.w);
  *(short4v*)(state + (size_t)i * 4) = b.v;
  *(short4v*)(state + (size_t)NtD + (size_t)i * 4) = b.v;
}

// ---------------- unified gather (state in bf16), unrolled over P and L ----------------
template<int L, int PP>
__device__ __forceinline__ float gath(const __hip_bfloat16* __restrict__ sect,
                                      const int* __restrict__ paths,
                                      const float* __restrict__ pw, int n, int N, int d)
{
  float pwv[L];
#pragma unroll
  for (int l = 0; l < L; ++l) pwv[l] = pw[l * 128 + d];
  float acc = 0.f;
  const int* ip0 = paths + (size_t)n * L;
#pragma unroll
  for (int p = 0; p < PP; ++p) {
    const int* ip = ip0 + (size_t)p * N * L;
    int idx[L];
#pragma unroll
    for (int l = 0; l < L; ++l) idx[l] = ip[l];
#pragma unroll
    for (int l = 0; l < L; ++l)
      acc = fmaf(pwv[l], __bfloat162float(sect[(size_t)idx[l] * 128 + d]), acc);
  }
  return acc;
}

template<int LMM, int LMD, int PP>
__global__ __launch_bounds__(256) void gather_all(
    const __hip_bfloat16* __restrict__ state,
    const int* __restrict__ paths_mm, const int* __restrict__ paths_dd, const int* __restrict__ paths_md,
    const float* __restrict__ pw1l, const float* __restrict__ pw2l,
    float* __restrict__ r, int Nm, int Nd)
{
  const int d = threadIdx.x & 127;
  const int nsub = threadIdx.x >> 7;
  const int g = blockIdx.x * 2 + nsub;
  const int Nt = Nm + Nd;
  if (g >= 2 * Nt) return;
  float acc;
  if (g < Nm)
    acc = gath<LMM, PP>(state, paths_mm, pw1l, g, Nm, d);
  else if (g < Nt)
    acc = gath<LMM, PP>(state + (size_t)Nm * 128, paths_dd, pw1l, g - Nm, Nd, d);
  else
    acc = gath<LMD, PP>(state + (size_t)Nt * 128, paths_md, pw2l, g - Nt, Nt, d);
  r[(size_t)g * 128 + d] = acc * (1.0f / (float)PP);
}

// runtime fallback
__global__ __launch_bounds__(256) void gather_einsum_rt(
    const __hip_bfloat16* __restrict__ feats, const int* __restrict__ paths,
    const float* __restrict__ pw, float* __restrict__ r, int N, int P, int L)
{
  const int d = threadIdx.x & 127;
  const int n = blockIdx.x * 2 + (threadIdx.x >> 7);
  if (n >= N) return;
  float acc = 0.f;
  for (int p = 0; p < P; ++p) {
    const int* ip = paths + ((size_t)p * N + n) * L;
    for (int l = 0; l < L; ++l)
      acc = fmaf(pw[l * 128 + d], __bfloat162float(feats[(size_t)ip[l] * 128 + d]), acc);
  }
  r[(size_t)n * 128 + d] = acc * (1.0f / (float)P);
}

// ---------------- fc layer: K=128, writes state as bf16 ----------------
template<int TR>
__global__ __launch_bounds__(256) void fc_all(
    const float* __restrict__ Rm, const float* __restrict__ W,
    const float* __restrict__ initb, __hip_bfloat16* __restrict__ state, int Ntot, int Nt)
{
  const int col = threadIdx.x & 127;
  const int rh  = __builtin_amdgcn_readfirstlane((int)(threadIdx.x >> 7));
  const int row0 = blockIdx.x * (2 * TR) + rh * TR;
  const float* arow[TR];
#pragma unroll
  for (int r = 0; r < TR; ++r) {
    int rr = row0 + r; if (rr > Ntot - 1) rr = Ntot - 1;
    arow[r] = Rm + (size_t)rr * 128;
  }
  float acc[TR];
#pragma unroll
  for (int r = 0; r < TR; ++r) acc[r] = 0.f;
#pragma unroll 4
  for (int k = 0; k < 128; k += 8) {
    float w[8];
#pragma unroll
    for (int kk = 0; kk < 8; ++kk) w[kk] = W[(size_t)(k + kk) * 128 + col];
#pragma unroll
    for (int r = 0; r < TR; ++r) {
      const float* ap = arow[r] + k;
#pragma unroll
      for (int kk = 0; kk < 8; ++kk) acc[r] = fmaf(ap[kk], w[kk], acc[r]);
    }
  }
#pragma unroll
  for (int r = 0; r < TR; ++r) {
    int rr = row0 + r;
    if (rr < Ntot) {
      int rbase = (rr < Nt) ? rr : rr - Nt;
      float v = ALPHA_ * initb[(size_t)rbase * 128 + col] + (1.f - ALPHA_) * fmaxf(acc[r], 0.f);
      state[(size_t)rr * 128 + col] = __float2bfloat16(v);
    }
  }
}

// MLP collapse (ILP-4)
__global__ void collapse1(const float* __restrict__ W0, const float* __restrict__ b0,
                          const float* __restrict__ W1, const float* __restrict__ b1,
                          float* __restrict__ w01, float* __restrict__ b01,
                          int E, int K0, int H1)
{
  int row = blockIdx.x; int c = threadIdx.x;
  if (c >= H1) return;
  const float* src; float base;
  if (row < E) { src = W0 + (size_t)row * K0; base = 0.f; }
  else         { src = b0; base = b1[c]; }
  float a0 = 0.f, a1 = 0.f, a2 = 0.f, a3 = 0.f;
#pragma unroll 4
  for (int k = 0; k < K0; k += 4) {
    a0 = fmaf(src[k + 0], W1[(size_t)(k + 0) * H1 + c], a0);
    a1 = fmaf(src[k + 1], W1[(size_t)(k + 1) * H1 + c], a1);
    a2 = fmaf(src[k + 2], W1[(size_t)(k + 2) * H1 + c], a2);
    a3 = fmaf(src[k + 3], W1[(size_t)(k + 3) * H1 + c], a3);
  }
  float acc = base + ((a0 + a1) + (a2 + a3));
  if (row < E) w01[(size_t)row * H1 + c] = acc; else b01[c] = acc;
}

__global__ void collapse2(const float* __restrict__ w01, const float* __restrict__ b01,
                          const float* __restrict__ W2, const float* __restrict__ b2,
                          float* __restrict__ w512, float* __restrict__ csc,
                          int E, int H1)
{
  int i = blockIdx.x * blockDim.x + threadIdx.x;
  if (i < E) {
    float a0 = 0.f, a1 = 0.f, a2 = 0.f, a3 = 0.f;
    for (int j = 0; j < H1; j += 4) {
      a0 = fmaf(w01[(size_t)i * H1 + j + 0], W2[j + 0], a0);
      a1 = fmaf(w01[(size_t)i * H1 + j + 1], W2[j + 1], a1);
      a2 = fmaf(w01[(size_t)i * H1 + j + 2], W2[j + 2], a2);
      a3 = fmaf(w01[(size_t)i * H1 + j + 3], W2[j + 3], a3);
    }
    w512[i] = (a0 + a1) + (a2 + a3);
  } else if (i == E) {
    float a = b2[0];
    for (int j = 0; j < H1; ++j) a = fmaf(b01[j], W2[j], a);
    csc[0] = a;
  }
}

__global__ __launch_bounds__(256) void node_partial(
    const __hip_bfloat16* __restrict__ Fmm, const __hip_bfloat16* __restrict__ Fdd,
    const __hip_bfloat16* __restrict__ Fmd,
    const float* __restrict__ w512, float* __restrict__ uv, int Nm, int Nt)
{
  int gid = blockIdx.x * blockDim.x + threadIdx.x;
  int wid = gid >> 6;
  int lane = threadIdx.x & 63;
  if (wid >= Nt) return;
  bool isM = wid < Nm;
  const __hip_bfloat16* X = isM ? (Fmm + (size_t)wid * 128) : (Fdd + (size_t)(wid - Nm) * 128);
  const __hip_bfloat16* Y = Fmd + (size_t)wid * 128;
  const float* w1 = w512 + (isM ? 0 : 256);
  const float* w2 = w1 + 128;
  float s = __bfloat162float(X[lane]) * w1[lane];
  s = fmaf(__bfloat162float(X[lane + 64]), w1[lane + 64], s);
  s = fmaf(__bfloat162float(Y[lane]), w2[lane], s);
  s = fmaf(__bfloat162float(Y[lane + 64]), w2[lane + 64], s);
#pragma unroll
  for (int off = 32; off > 0; off >>= 1) s += __shfl_down(s, off);
  if (lane == 0) uv[wid] = s;
}

__global__ __launch_bounds__(256) void score_kernel(
    const int* __restrict__ samples, const float* __restrict__ u, const float* __restrict__ v,
    const float* __restrict__ csc, float* __restrict__ out, int S)
{
  int s = blockIdx.x * blockDim.x + threadIdx.x;
  if (s >= S) return;
  const int2 ij = ((const int2*)samples)[s];
  float x = u[ij.x] + v[ij.y] + csc[0];
  out[s] = 1.0f / (1.0f + expf(-x));
}

extern "C" void kernel_launch(void* const* d_in, const int* in_sizes, int n_in,
                              void* d_out, int out_size, void* d_ws, size_t ws_size,
                              hipStream_t stream)
{
  const int*   paths_mm = (const int*)d_in[0];
  const int*   paths_dd = (const int*)d_in[1];
  const int*   paths_md = (const int*)d_in[2];
  const float* miRNA    = (const float*)d_in[3];
  const float* disease  = (const float*)d_in[4];
  const int*   samples  = (const int*)d_in[5];
  const float* Wm  = (const float*)d_in[6];
  const float* Wd  = (const float*)d_in[7];
  const float* pw1 = (const float*)d_in[8];
  const float* pw2 = (const float*)d_in[9];
  const float* fcW = (const float*)d_in[10];
  const float* W0  = (const float*)d_in[11];
  const float* b0  = (const float*)d_in[12];
  const float* W1  = (const float*)d_in[13];
  const float* b1  = (const float*)d_in[14];
  const float* W2  = (const float*)d_in[15];
  const float* b2  = (const float*)d_in[16];

  const int D  = 128;
  const int Nm = in_sizes[6] / D;
  const int Nd = in_sizes[7] / D;
  const int Nt = Nm + Nd;
  const int S  = in_sizes[5] / 2;
  const int layers = in_sizes[10] / (D * D);
  const int L1 = in_sizes[8] / (layers * D);
  const int L2 = in_sizes[9] / (layers * D);
  const int P  = in_sizes[0] / (Nm * L1);
  const int E  = 4 * D;
  const int K0 = in_sizes[12];
  const int H1 = in_sizes[14];
  const int Kpm = cdiv(Nm, 128) * 128;   // 8064
  const int Kpd = cdiv(Nd, 128) * 128;   // 6016
  const size_t NtD = (size_t)Nt * D;

  float* out = (float*)d_out;
  float* ws  = (float*)d_ws;
  size_t off = 0;
  float* init  = ws + off; off += NtD;
  __hip_bfloat16* state = (__hip_bfloat16*)(ws + off); off += NtD;
  float* bufR  = ws + off; off += 2 * NtD;
  float* w01   = ws + off; off += (size_t)E * H1;
  float* b01   = ws + off; off += H1;
  float* w512  = ws + off; off += E;
  float* csc   = ws + off; off += 1;
  float* uv    = ws + off; off += Nt;
  __hip_bfloat16* WtTm = (__hip_bfloat16*)(ws + off); off += (size_t)D * Kpm / 2;
  __hip_bfloat16* WtTd = (__hip_bfloat16*)(ws + off); off += (size_t)D * Kpd / 2;
  float* pextra = ws + off;
  const bool big_ws = (off + 2 * NtD) * 4 <= ws_size;
  (void)n_in; (void)out_size;

  // 1. tile-major bf16 weight transposes (32k tiles; Kpm/Kpd are multiples of 128 -> of 32)
  make_wtT<<<Kpm / 32, 256, 0, stream>>>(Wm, WtTm, Nm);
  make_wtT<<<Kpd / 32, 256, 0, stream>>>(Wd, WtTd, Nd);

  // 2. MLP collapse
  collapse1<<<E + 1, 64, 0, stream>>>(W0, b0, W1, b1, w01, b01, E, K0, H1);
  collapse2<<<cdiv(E + 1, 256), 256, 0, stream>>>(w01, b01, W2, b2, w512, csc, E, H1);

  // 3. init GEMMs (copy-like staged MFMA)
  {
    int nbm = Kpm / 128, nbd = cdiv(Nd, 128);
    int n4 = (int)(NtD / 4);
    P8 parr;
    parr.p[0] = init;
    parr.p[1] = bufR;
    parr.p[2] = bufR + NtD;
    if (big_ws) {
      parr.p[3] = pextra;
      parr.p[4] = pextra + NtD;
      init_mfma5<5><<<(nbm + nbd) * 5, 512, 0, stream>>>(
          miRNA, WtTm, Nm, nbm, disease, WtTd, Nd, Kpd, parr);
      combineN<5><<<cdiv(n4, 256), 256, 0, stream>>>(parr, (float4v*)init, state, n4, (int)NtD);
    } else {
      init_mfma5<3><<<(nbm + nbd) * 3, 512, 0, stream>>>(
          miRNA, WtTm, Nm, nbm, disease, WtTd, Nd, Kpd, parr);
      combineN<3><<<cdiv(n4, 256), 256, 0, stream>>>(parr, (float4v*)init, state, n4, (int)NtD);
    }
  }

  // 4. fused path-layer chains (state bf16, residual from f32 init)
  constexpr int TR = 8;
  for (int l = 0; l < layers; ++l) {
    const float* pw1l = pw1 + (size_t)l * L1 * D;
    const float* pw2l = pw2 + (size_t)l * L2 * D;
    if (L1 == 4 && L2 == 6 && P == 8) {
      gather_all<4, 6, 8><<<Nt, 256, 0, stream>>>(
          state, paths_mm, paths_dd, paths_md, pw1l, pw2l, bufR, Nm, Nd);
    } else {
      gather_einsum_rt<<<cdiv(Nm, 2), 256, 0, stream>>>(state, paths_mm, pw1l, bufR, Nm, P, L1);
      gather_einsum_rt<<<cdiv(Nd, 2), 256, 0, stream>>>(state + (size_t)Nm * D, paths_dd, pw1l,
                                                        bufR + (size_t)Nm * D, Nd, P, L1);
      gather_einsum_rt<<<cdiv(Nt, 2), 256, 0, stream>>>(state + NtD, paths_md, pw2l,
                                                        bufR + NtD, Nt, P, L2);
    }
    fc_all<TR><<<cdiv(2 * Nt, 2 * TR), 256, 0, stream>>>(
        bufR, fcW + (size_t)l * D * D, init, state, 2 * Nt, Nt);
  }

  // 5. per-node partial dots + scoring
  node_partial<<<cdiv(Nt * 64, 256), 256, 0, stream>>>(
      state, state + (size_t)Nm * D, state + NtD, w512, uv, Nm, Nt);
  score_kernel<<<cdiv(S, 256), 256, 0, stream>>>(samples, uv, uv + Nm, csc, out, S);
}

// Round 11
// 278.254 us; speedup vs baseline: 1.5754x; 1.2225x over previous
//
#include <hip/hip_runtime.h>
#include <hip/hip_bf16.h>
#include <cstdint>
#include <cstddef>

#define ALPHA_ 0.1f

static inline int cdiv(int a, int b) { return (a + b - 1) / b; }

typedef __attribute__((ext_vector_type(8))) short short8;
typedef __attribute__((ext_vector_type(4))) short short4v;
typedef __attribute__((ext_vector_type(4))) float float4v;

struct P8 { float* p[8]; };

__device__ __forceinline__ void gload_lds16(const void* g, void* l) {
  __builtin_amdgcn_global_load_lds((const __attribute__((address_space(1))) unsigned int*)g,
                                   (__attribute__((address_space(3))) unsigned int*)l,
                                   16, 0, 0);
}

// ---------------- WtT builder: per-32k-tile [kg][col][e] bf16 layout of W (K x 128) -------
__global__ __launch_bounds__(256) void make_wtT(const float* __restrict__ W,
                                                __hip_bfloat16* __restrict__ WtT,
                                                int K)
{
  __shared__ float tile[32][129];
  const int t  = threadIdx.x;
  const int s  = blockIdx.x;
  const int k0 = s * 32;
#pragma unroll
  for (int pass = 0; pass < 4; ++pass) {
    int idx = pass * 1024 + t * 4;
    int k = idx >> 7, c = idx & 127;
    float4v v;
    const float* src = W + (size_t)(k0 + k) * 128 + c;
    if (k0 + k < K) v = *(const float4v*)src;
    else            v = (float4v){0.f, 0.f, 0.f, 0.f};
    tile[k][c] = v.x; tile[k][c + 1] = v.y; tile[k][c + 2] = v.z; tile[k][c + 3] = v.w;
  }
  __syncthreads();
#pragma unroll
  for (int pass = 0; pass < 16; ++pass) {
    int idx = pass * 256 + t;
    int kg = idx >> 10, rem = idx & 1023;
    int c = rem >> 3, e = rem & 7;
    WtT[(size_t)s * 4096 + idx] = __float2bfloat16(tile[kg * 8 + e][c]);
  }
}

// ---------------- init GEMM (frozen from R10: best-known, ~157us) ----------
template<int KSPLIT>
__global__ __launch_bounds__(512) void init_mfma5(
    const float* __restrict__ Am, const __hip_bfloat16* __restrict__ Wtm, int Nm_, int nbm,
    const float* __restrict__ Ad, const __hip_bfloat16* __restrict__ Wtd, int Nd_, int Kpd,
    P8 parr)
{
  __shared__ __align__(16) __hip_bfloat16 lds_a[128 * 128];   // 32KB
  __shared__ __align__(16) __hip_bfloat16 lds_w[4 * 4096];    // 32KB

  const int t    = threadIdx.x;
  const int lane = t & 63;
  const int wv   = t >> 6;

  const int chunk = blockIdx.x % KSPLIT;
  int mb          = blockIdx.x / KSPLIT;

  const float* A; const __hip_bfloat16* Wt; int N, K, Kpad, rowoff, rb;
  if (mb < nbm) { A = Am; Wt = Wtm; N = Nm_; K = Nm_; Kpad = nbm * 128; rowoff = 0;   rb = mb; }
  else          { A = Ad; Wt = Wtd; N = Nd_; K = Nd_; Kpad = Kpd;       rowoff = Nm_; rb = mb - nbm; }

  float* Cp = parr.p[chunk];

  const int St = Kpad / 128;
  const int s0 = (int)(((long)St * chunk) / KSPLIT);
  const int s1 = (int)(((long)St * (chunk + 1)) / KSPLIT);

  const int row_g0 = rb * 128;

  const float* apass[8];
  int aw_byte[8];
#pragma unroll
  for (int p = 0; p < 8; ++p) {
    int f   = p * 512 + t;
    int row = f >> 5, kq = f & 31;
    int rg  = row_g0 + row; if (rg > N - 1) rg = N - 1;
    apass[p] = A + (size_t)rg * K + kq * 4;
    int c = kq >> 1, h = kq & 1;
    aw_byte[p] = row * 256 + ((c ^ (row & 15)) << 4) + h * 8;
  }

  const int rloc  = lane & 15;
  const int kg    = lane >> 4;
  const int row_l = wv * 16 + rloc;
  int a_rbyte[4];
#pragma unroll
  for (int sub = 0; sub < 4; ++sub) {
    int c = sub * 4 + kg;
    a_rbyte[sub] = row_l * 256 + ((c ^ (row_l & 15)) << 4);
  }
  int w_roff[8];
#pragma unroll
  for (int mt = 0; mt < 8; ++mt)
    w_roff[mt] = (mt * 16 + rloc) * 8;

  float4v acc[8];
#pragma unroll
  for (int mt = 0; mt < 8; ++mt) acc[mt] = (float4v){0.f, 0.f, 0.f, 0.f};

  const char* wt_bytes = (const char*)Wt;

  for (int s = s0; s < s1; ++s) {
#pragma unroll
    for (int i = 0; i < 4; ++i) {
      gload_lds16(wt_bytes + (size_t)(s * 4) * 8192 + (size_t)(i * 512 + wv * 64 + lane) * 16,
                  (char*)lds_w + (size_t)(i * 512 + wv * 64) * 16);
    }
    float4v av[8];
    const int kb = s * 128;
#pragma unroll
    for (int p = 0; p < 8; ++p) {
      const float* src = apass[p] + kb;
      ptrdiff_t rel = (src - A);
      av[p] = *(const float4v*)(A + ((rel > (ptrdiff_t)((size_t)(N) * K - 4)) ? ((size_t)N * K - 4) : rel));
    }
#pragma unroll
    for (int p = 0; p < 8; ++p) {
      union { short4v v; __hip_bfloat16 h[4]; } pk;
      pk.h[0] = __float2bfloat16(av[p].x); pk.h[1] = __float2bfloat16(av[p].y);
      pk.h[2] = __float2bfloat16(av[p].z); pk.h[3] = __float2bfloat16(av[p].w);
      *(short4v*)((char*)lds_a + aw_byte[p]) = pk.v;
    }
    __syncthreads();

#pragma unroll
    for (int sub = 0; sub < 4; ++sub) {
      short8 afrag = *(const short8*)((const char*)lds_a + a_rbyte[sub]);
      const __hip_bfloat16* lw = lds_w + sub * 4096 + kg * 1024;
#pragma unroll
      for (int mt = 0; mt < 8; ++mt) {
        short8 wfrag = *(const short8*)(lw + w_roff[mt]);
        acc[mt] = __builtin_amdgcn_mfma_f32_16x16x32_bf16(wfrag, afrag, acc[mt], 0, 0, 0);
      }
    }
    __syncthreads();
  }

  int row = row_g0 + row_l;
  if (row < N) {
    float* dst = Cp + (size_t)(rowoff + row) * 128 + kg * 4;
#pragma unroll
    for (int mt = 0; mt < 8; ++mt)
      *(float4v*)(dst + mt * 16) = acc[mt];
  }
}

// sum NP partials -> init (f32) + both sections of stateA (bf16)
template<int NP>
__global__ __launch_bounds__(256) void combineN(
    P8 parr, float4v* __restrict__ o_init, __hip_bfloat16* __restrict__ state,
    int n4, int NtD)
{
  int i = blockIdx.x * 256 + threadIdx.x;
  if (i >= n4) return;
  float4v s = ((const float4v*)parr.p[0])[i];
#pragma unroll
  for (int j = 1; j < NP; ++j) {
    float4v x = ((const float4v*)parr.p[j])[i];
    s.x += x.x; s.y += x.y; s.z += x.z; s.w += x.w;
  }
  o_init[i] = s;
  union { short4v v; __hip_bfloat16 h[4]; } b;
  b.h[0] = __float2bfloat16(s.x); b.h[1] = __float2bfloat16(s.y);
  b.h[2] = __float2bfloat16(s.z); b.h[3] = __float2bfloat16(s.w);
  *(short4v*)(state + (size_t)i * 4) = b.v;
  *(short4v*)(state + (size_t)NtD + (size_t)i * 4) = b.v;
}

// ---------------- gather core ----------------
template<int L, int PP>
__device__ __forceinline__ float gath(const __hip_bfloat16* __restrict__ sect,
                                      const int* __restrict__ paths,
                                      const float* __restrict__ pw, int n, int N, int d)
{
  float pwv[L];
#pragma unroll
  for (int l = 0; l < L; ++l) pwv[l] = pw[l * 128 + d];
  float acc = 0.f;
  const int* ip0 = paths + (size_t)n * L;
#pragma unroll
  for (int p = 0; p < PP; ++p) {
    const int* ip = ip0 + (size_t)p * N * L;
    int idx[L];
#pragma unroll
    for (int l = 0; l < L; ++l) idx[l] = ip[l];
#pragma unroll
    for (int l = 0; l < L; ++l)
      acc = fmaf(pwv[l], __bfloat162float(sect[(size_t)idx[l] * 128 + d]), acc);
  }
  return acc;
}

// ---------------- FUSED layer: gather 16 nodes -> LDS, then fc + residual ----------------
// stateIn/stateOut ping-pong (race-free). Sections: [mm Nm; dd Nd; md Nt], each %16==0.
template<int LMM, int LMD, int PP>
__global__ __launch_bounds__(256) void layer_fused(
    const __hip_bfloat16* __restrict__ stateIn,
    const int* __restrict__ paths_mm, const int* __restrict__ paths_dd, const int* __restrict__ paths_md,
    const float* __restrict__ pw1l, const float* __restrict__ pw2l,
    const float* __restrict__ fcWl, const float* __restrict__ initb,
    __hip_bfloat16* __restrict__ stateOut,
    int Nm, int Nd, int nbm, int nbd)
{
  __shared__ float r_lds[16][128];
  const int t  = threadIdx.x;
  const int Nt = Nm + Nd;
  int b = blockIdx.x;

  const __hip_bfloat16* sect; const int* paths; const float* pw;
  int N, rowbase, nb; bool md;
  if (b < nbm)            { sect = stateIn;                     paths = paths_mm; pw = pw1l; N = Nm; rowbase = 0;  nb = b;             md = false; }
  else if (b < nbm + nbd) { sect = stateIn + (size_t)Nm * 128;  paths = paths_dd; pw = pw1l; N = Nd; rowbase = Nm; nb = b - nbm;       md = false; }
  else                    { sect = stateIn + (size_t)Nt * 128;  paths = paths_md; pw = pw2l; N = Nt; rowbase = Nt; nb = b - nbm - nbd; md = true;  }

  const int d   = t & 127;
  const int sub = t >> 7;           // wave-uniform
  const int n0  = nb * 16;

  // phase 1: gather 16 node-rows into LDS (slot wave-uniform -> scalar index loads)
#pragma unroll
  for (int i = 0; i < 8; ++i) {
    int slot = sub + 2 * i;
    int n = n0 + slot;
    int ng = (n < N) ? n : (N - 1);
    float acc = md ? gath<LMD, PP>(sect, paths, pw, ng, N, d)
                   : gath<LMM, PP>(sect, paths, pw, ng, N, d);
    r_lds[slot][d] = acc * (1.0f / (float)PP);
  }
  __syncthreads();

  // phase 2: fc (rows from LDS broadcast, W coalesced) + residual, write bf16
  const int col = d;
  const int rh  = sub;              // 8 rows per half
  float acc2[8];
#pragma unroll
  for (int j = 0; j < 8; ++j) acc2[j] = 0.f;
#pragma unroll 4
  for (int k = 0; k < 128; k += 8) {
    float w[8];
#pragma unroll
    for (int kk = 0; kk < 8; ++kk) w[kk] = fcWl[(size_t)(k + kk) * 128 + col];
#pragma unroll
    for (int j = 0; j < 8; ++j) {
      const float* rp = &r_lds[rh * 8 + j][k];
#pragma unroll
      for (int kk = 0; kk < 8; ++kk) acc2[j] = fmaf(rp[kk], w[kk], acc2[j]);
    }
  }
#pragma unroll
  for (int j = 0; j < 8; ++j) {
    int n = n0 + rh * 8 + j;
    if (n < N) {
      int rr = rowbase + n;
      int rbase = (rr < Nt) ? rr : rr - Nt;
      float v = ALPHA_ * initb[(size_t)rbase * 128 + col] + (1.f - ALPHA_) * fmaxf(acc2[j], 0.f);
      stateOut[(size_t)rr * 128 + col] = __float2bfloat16(v);
    }
  }
}

// ---------------- unfused fallbacks (generic shapes) ----------------
__global__ __launch_bounds__(256) void gather_einsum_rt(
    const __hip_bfloat16* __restrict__ feats, const int* __restrict__ paths,
    const float* __restrict__ pw, float* __restrict__ r, int N, int P, int L)
{
  const int d = threadIdx.x & 127;
  const int n = blockIdx.x * 2 + (threadIdx.x >> 7);
  if (n >= N) return;
  float acc = 0.f;
  for (int p = 0; p < P; ++p) {
    const int* ip = paths + ((size_t)p * N + n) * L;
    for (int l = 0; l < L; ++l)
      acc = fmaf(pw[l * 128 + d], __bfloat162float(feats[(size_t)ip[l] * 128 + d]), acc);
  }
  r[(size_t)n * 128 + d] = acc * (1.0f / (float)P);
}

template<int TR>
__global__ __launch_bounds__(256) void fc_all(
    const float* __restrict__ Rm, const float* __restrict__ W,
    const float* __restrict__ initb, __hip_bfloat16* __restrict__ state, int Ntot, int Nt)
{
  const int col = threadIdx.x & 127;
  const int rh  = __builtin_amdgcn_readfirstlane((int)(threadIdx.x >> 7));
  const int row0 = blockIdx.x * (2 * TR) + rh * TR;
  const float* arow[TR];
#pragma unroll
  for (int r = 0; r < TR; ++r) {
    int rr = row0 + r; if (rr > Ntot - 1) rr = Ntot - 1;
    arow[r] = Rm + (size_t)rr * 128;
  }
  float acc[TR];
#pragma unroll
  for (int r = 0; r < TR; ++r) acc[r] = 0.f;
#pragma unroll 4
  for (int k = 0; k < 128; k += 8) {
    float w[8];
#pragma unroll
    for (int kk = 0; kk < 8; ++kk) w[kk] = W[(size_t)(k + kk) * 128 + col];
#pragma unroll
    for (int r = 0; r < TR; ++r) {
      const float* ap = arow[r] + k;
#pragma unroll
      for (int kk = 0; kk < 8; ++kk) acc[r] = fmaf(ap[kk], w[kk], acc[r]);
    }
  }
#pragma unroll
  for (int r = 0; r < TR; ++r) {
    int rr = row0 + r;
    if (rr < Ntot) {
      int rbase = (rr < Nt) ? rr : rr - Nt;
      float v = ALPHA_ * initb[(size_t)rbase * 128 + col] + (1.f - ALPHA_) * fmaxf(acc[r], 0.f);
      state[(size_t)rr * 128 + col] = __float2bfloat16(v);
    }
  }
}

// MLP collapse
__global__ void collapse1(const float* __restrict__ W0, const float* __restrict__ b0,
                          const float* __restrict__ W1, const float* __restrict__ b1,
                          float* __restrict__ w01, float* __restrict__ b01,
                          int E, int K0, int H1)
{
  int row = blockIdx.x; int c = threadIdx.x;
  if (c >= H1) return;
  const float* src; float base;
  if (row < E) { src = W0 + (size_t)row * K0; base = 0.f; }
  else         { src = b0; base = b1[c]; }
  float a0 = 0.f, a1 = 0.f, a2 = 0.f, a3 = 0.f;
#pragma unroll 4
  for (int k = 0; k < K0; k += 4) {
    a0 = fmaf(src[k + 0], W1[(size_t)(k + 0) * H1 + c], a0);
    a1 = fmaf(src[k + 1], W1[(size_t)(k + 1) * H1 + c], a1);
    a2 = fmaf(src[k + 2], W1[(size_t)(k + 2) * H1 + c], a2);
    a3 = fmaf(src[k + 3], W1[(size_t)(k + 3) * H1 + c], a3);
  }
  float acc = base + ((a0 + a1) + (a2 + a3));
  if (row < E) w01[(size_t)row * H1 + c] = acc; else b01[c] = acc;
}

__global__ void collapse2(const float* __restrict__ w01, const float* __restrict__ b01,
                          const float* __restrict__ W2, const float* __restrict__ b2,
                          float* __restrict__ w512, float* __restrict__ csc,
                          int E, int H1)
{
  int i = blockIdx.x * blockDim.x + threadIdx.x;
  if (i < E) {
    float a0 = 0.f, a1 = 0.f, a2 = 0.f, a3 = 0.f;
    for (int j = 0; j < H1; j += 4) {
      a0 = fmaf(w01[(size_t)i * H1 + j + 0], W2[j + 0], a0);
      a1 = fmaf(w01[(size_t)i * H1 + j + 1], W2[j + 1], a1);
      a2 = fmaf(w01[(size_t)i * H1 + j + 2], W2[j + 2], a2);
      a3 = fmaf(w01[(size_t)i * H1 + j + 3], W2[j + 3], a3);
    }
    w512[i] = (a0 + a1) + (a2 + a3);
  } else if (i == E) {
    float a = b2[0];
    for (int j = 0; j < H1; ++j) a = fmaf(b01[j], W2[j], a);
    csc[0] = a;
  }
}

__global__ __launch_bounds__(256) void node_partial(
    const __hip_bfloat16* __restrict__ Fmm, const __hip_bfloat16* __restrict__ Fdd,
    const __hip_bfloat16* __restrict__ Fmd,
    const float* __restrict__ w512, float* __restrict__ uv, int Nm, int Nt)
{
  int gid = blockIdx.x * blockDim.x + threadIdx.x;
  int wid = gid >> 6;
  int lane = threadIdx.x & 63;
  if (wid >= Nt) return;
  bool isM = wid < Nm;
  const __hip_bfloat16* X = isM ? (Fmm + (size_t)wid * 128) : (Fdd + (size_t)(wid - Nm) * 128);
  const __hip_bfloat16* Y = Fmd + (size_t)wid * 128;
  const float* w1 = w512 + (isM ? 0 : 256);
  const float* w2 = w1 + 128;
  float s = __bfloat162float(X[lane]) * w1[lane];
  s = fmaf(__bfloat162float(X[lane + 64]), w1[lane + 64], s);
  s = fmaf(__bfloat162float(Y[lane]), w2[lane], s);
  s = fmaf(__bfloat162float(Y[lane + 64]), w2[lane + 64], s);
#pragma unroll
  for (int off = 32; off > 0; off >>= 1) s += __shfl_down(s, off);
  if (lane == 0) uv[wid] = s;
}

__global__ __launch_bounds__(256) void score_kernel(
    const int* __restrict__ samples, const float* __restrict__ u, const float* __restrict__ v,
    const float* __restrict__ csc, float* __restrict__ out, int S)
{
  int s = blockIdx.x * blockDim.x + threadIdx.x;
  if (s >= S) return;
  const int2 ij = ((const int2*)samples)[s];
  float x = u[ij.x] + v[ij.y] + csc[0];
  out[s] = 1.0f / (1.0f + expf(-x));
}

extern "C" void kernel_launch(void* const* d_in, const int* in_sizes, int n_in,
                              void* d_out, int out_size, void* d_ws, size_t ws_size,
                              hipStream_t stream)
{
  const int*   paths_mm = (const int*)d_in[0];
  const int*   paths_dd = (const int*)d_in[1];
  const int*   paths_md = (const int*)d_in[2];
  const float* miRNA    = (const float*)d_in[3];
  const float* disease  = (const float*)d_in[4];
  const int*   samples  = (const int*)d_in[5];
  const float* Wm  = (const float*)d_in[6];
  const float* Wd  = (const float*)d_in[7];
  const float* pw1 = (const float*)d_in[8];
  const float* pw2 = (const float*)d_in[9];
  const float* fcW = (const float*)d_in[10];
  const float* W0  = (const float*)d_in[11];
  const float* b0  = (const float*)d_in[12];
  const float* W1  = (const float*)d_in[13];
  const float* b1  = (const float*)d_in[14];
  const float* W2  = (const float*)d_in[15];
  const float* b2  = (const float*)d_in[16];

  const int D  = 128;
  const int Nm = in_sizes[6] / D;
  const int Nd = in_sizes[7] / D;
  const int Nt = Nm + Nd;
  const int S  = in_sizes[5] / 2;
  const int layers = in_sizes[10] / (D * D);
  const int L1 = in_sizes[8] / (layers * D);
  const int L2 = in_sizes[9] / (layers * D);
  const int P  = in_sizes[0] / (Nm * L1);
  const int E  = 4 * D;
  const int K0 = in_sizes[12];
  const int H1 = in_sizes[14];
  const int Kpm = cdiv(Nm, 128) * 128;   // 8064
  const int Kpd = cdiv(Nd, 128) * 128;   // 6016
  const size_t NtD = (size_t)Nt * D;

  float* out = (float*)d_out;
  float* ws  = (float*)d_ws;
  size_t off = 0;
  float* init   = ws + off; off += NtD;                              // f32 summed init
  __hip_bfloat16* stateA = (__hip_bfloat16*)(ws + off); off += NtD;  // 2*NtD bf16
  __hip_bfloat16* stateB = (__hip_bfloat16*)(ws + off); off += NtD;  // 2*NtD bf16
  float* w01    = ws + off; off += (size_t)E * H1;
  float* b01    = ws + off; off += H1;
  float* w512   = ws + off; off += E;
  float* csc    = ws + off; off += 1;
  float* uv     = ws + off; off += Nt;
  __hip_bfloat16* WtTm = (__hip_bfloat16*)(ws + off); off += (size_t)D * Kpm / 2;
  __hip_bfloat16* WtTd = (__hip_bfloat16*)(ws + off); off += (size_t)D * Kpd / 2;
  float* pextra = ws + off;
  const bool big_ws = (off + 3 * NtD) * 4 <= ws_size;
  (void)n_in; (void)out_size;

  // 1. tile-major bf16 weight transposes
  make_wtT<<<Kpm / 32, 256, 0, stream>>>(Wm, WtTm, Nm);
  make_wtT<<<Kpd / 32, 256, 0, stream>>>(Wd, WtTd, Nd);

  // 2. MLP collapse
  collapse1<<<E + 1, 64, 0, stream>>>(W0, b0, W1, b1, w01, b01, E, K0, H1);
  collapse2<<<cdiv(E + 1, 256), 256, 0, stream>>>(w01, b01, W2, b2, w512, csc, E, H1);

  // 3. init GEMMs (frozen R10 structure). Partials: init, stateB(as f32 scratch), pextra[0..2].
  {
    int nbm = Kpm / 128, nbd = cdiv(Nd, 128);
    int n4 = (int)(NtD / 4);
    P8 parr;
    parr.p[0] = init;
    parr.p[1] = (float*)stateB;      // free until layer 0 writes it (combineN runs first)
    if (big_ws) {
      parr.p[2] = pextra;
      parr.p[3] = pextra + NtD;
      parr.p[4] = pextra + 2 * NtD;
      init_mfma5<5><<<(nbm + nbd) * 5, 512, 0, stream>>>(
          miRNA, WtTm, Nm, nbm, disease, WtTd, Nd, Kpd, parr);
      combineN<5><<<cdiv(n4, 256), 256, 0, stream>>>(parr, (float4v*)init, stateA, n4, (int)NtD);
    } else {
      parr.p[2] = pextra;
      init_mfma5<3><<<(nbm + nbd) * 3, 512, 0, stream>>>(
          miRNA, WtTm, Nm, nbm, disease, WtTd, Nd, Kpd, parr);
      combineN<3><<<cdiv(n4, 256), 256, 0, stream>>>(parr, (float4v*)init, stateA, n4, (int)NtD);
    }
  }

  // 4. path layers: fused gather+fc with ping-pong state
  const bool fuse_ok = (L1 == 4 && L2 == 6 && P == 8 &&
                        Nm % 16 == 0 && Nd % 16 == 0 && Nt % 16 == 0);
  __hip_bfloat16* cur = stateA;
  __hip_bfloat16* nxt = stateB;
  for (int l = 0; l < layers; ++l) {
    const float* pw1l = pw1 + (size_t)l * L1 * D;
    const float* pw2l = pw2 + (size_t)l * L2 * D;
    const float* fcWl = fcW + (size_t)l * D * D;
    if (fuse_ok) {
      int nbm16 = Nm / 16, nbd16 = Nd / 16, nbt16 = Nt / 16;
      layer_fused<4, 6, 8><<<nbm16 + nbd16 + nbt16, 256, 0, stream>>>(
          cur, paths_mm, paths_dd, paths_md, pw1l, pw2l, fcWl, init, nxt,
          Nm, Nd, nbm16, nbd16);
    } else {
      float* bufR = pextra;   // generic fallback path
      gather_einsum_rt<<<cdiv(Nm, 2), 256, 0, stream>>>(cur, paths_mm, pw1l, bufR, Nm, P, L1);
      gather_einsum_rt<<<cdiv(Nd, 2), 256, 0, stream>>>(cur + (size_t)Nm * D, paths_dd, pw1l,
                                                        bufR + (size_t)Nm * D, Nd, P, L1);
      gather_einsum_rt<<<cdiv(Nt, 2), 256, 0, stream>>>(cur + NtD, paths_md, pw2l,
                                                        bufR + NtD, Nt, P, L2);
      fc_all<8><<<cdiv(2 * Nt, 16), 256, 0, stream>>>(
          bufR, fcWl, init, nxt, 2 * Nt, Nt);
    }
    __hip_bfloat16* tmp = cur; cur = nxt; nxt = tmp;
  }

  // 5. per-node partial dots + scoring (cur holds the final state)
  node_partial<<<cdiv(Nt * 64, 256), 256, 0, stream>>>(
      cur, cur + (size_t)Nm * D, cur + NtD, w512, uv, Nm, Nt);
  score_kernel<<<cdiv(S, 256), 256, 0, stream>>>(samples, uv, uv + Nm, csc, out, S);
}

// Round 12
// 269.961 us; speedup vs baseline: 1.6238x; 1.0307x over previous
//
#include <hip/hip_runtime.h>
#include <hip/hip_bf16.h>
#include <cstdint>
#include <cstddef>

#define ALPHA_ 0.1f

static inline int cdiv(int a, int b) { return (a + b - 1) / b; }

typedef __attribute__((ext_vector_type(8))) short short8;
typedef __attribute__((ext_vector_type(4))) short short4v;
typedef __attribute__((ext_vector_type(4))) float float4v;

struct P12 { float* p[12]; };

__device__ __forceinline__ void gload_lds16(const void* g, void* l) {
  __builtin_amdgcn_global_load_lds((const __attribute__((address_space(1))) unsigned int*)g,
                                   (__attribute__((address_space(3))) unsigned int*)l,
                                   16, 0, 0);
}

// ---------------- WtT builder: per-32k-tile [kg][col][e] bf16 layout of W (K x 128) -------
__global__ __launch_bounds__(256) void make_wtT(const float* __restrict__ W,
                                                __hip_bfloat16* __restrict__ WtT,
                                                int K)
{
  __shared__ float tile[32][129];
  const int t  = threadIdx.x;
  const int s  = blockIdx.x;
  const int k0 = s * 32;
#pragma unroll
  for (int pass = 0; pass < 4; ++pass) {
    int idx = pass * 1024 + t * 4;
    int k = idx >> 7, c = idx & 127;
    float4v v;
    const float* src = W + (size_t)(k0 + k) * 128 + c;
    if (k0 + k < K) v = *(const float4v*)src;
    else            v = (float4v){0.f, 0.f, 0.f, 0.f};
    tile[k][c] = v.x; tile[k][c + 1] = v.y; tile[k][c + 2] = v.z; tile[k][c + 3] = v.w;
  }
  __syncthreads();
#pragma unroll
  for (int pass = 0; pass < 16; ++pass) {
    int idx = pass * 256 + t;
    int kg = idx >> 10, rem = idx & 1023;
    int c = rem >> 3, e = rem & 7;
    WtT[(size_t)s * 4096 + idx] = __float2bfloat16(tile[kg * 8 + e][c]);
  }
}

// ---------------- init GEMM: BM=256, BK=64 (W traffic halved), 2-phase, 48KB LDS ----------
// 512 thr = 8 waves; wave wv owns rows wv*32..+32 (two 16-row groups) x all 128 cols.
// A: copy-like staging (1KB wave-runs) -> swizzled LDS [256][64]bf16 (XOR chunk with row&7).
// W: two 8KB 32k-tiles per step via linear glds from [kg][col][e] WtT.
template<int KSPLIT>
__global__ __launch_bounds__(512, 4) void init_mfma6(
    const float* __restrict__ Am, const __hip_bfloat16* __restrict__ Wtm, int Nm_, int nbm, int Kpm,
    const float* __restrict__ Ad, const __hip_bfloat16* __restrict__ Wtd, int Nd_, int Kpd,
    P12 parr)
{
  __shared__ __align__(16) __hip_bfloat16 lds_a[256 * 64];   // 32KB
  __shared__ __align__(16) __hip_bfloat16 lds_w[2 * 4096];   // 16KB

  const int t    = threadIdx.x;
  const int lane = t & 63;
  const int wv   = t >> 6;

  const int chunk = blockIdx.x % KSPLIT;
  int mb          = blockIdx.x / KSPLIT;

  const float* A; const __hip_bfloat16* Wt; int N, K, Kpad, rowoff, rb;
  if (mb < nbm) { A = Am; Wt = Wtm; N = Nm_; K = Nm_; Kpad = Kpm; rowoff = 0;   rb = mb; }
  else          { A = Ad; Wt = Wtd; N = Nd_; K = Nd_; Kpad = Kpd; rowoff = Nm_; rb = mb - nbm; }

  float* Cp = parr.p[chunk];

  const int St = Kpad / 64;
  const int s0 = (int)(((long)St * chunk) / KSPLIT);
  const int s1 = (int)(((long)St * (chunk + 1)) / KSPLIT);

  const int row_g0 = rb * 256;

  // ---- A staging map: pass p, flat f = p*512 + t (float4 units); row = f>>4, kq = f&15 ----
  const float* apass[8];
  int aw_byte[8];
#pragma unroll
  for (int p = 0; p < 8; ++p) {
    int f   = p * 512 + t;
    int row = f >> 4, kq = f & 15;
    int rg  = row_g0 + row; if (rg > N - 1) rg = N - 1;
    apass[p] = A + (size_t)rg * K + kq * 4;
    int c = kq >> 1, h = kq & 1;
    aw_byte[p] = row * 128 + ((c ^ (row & 7)) << 4) + h * 8;
  }

  // ---- compute-side frag offsets ----
  const int rloc = lane & 15;
  const int kg   = lane >> 4;
  int a_rbyte[2][2];   // [g][sub]
#pragma unroll
  for (int g = 0; g < 2; ++g) {
    int row_l = wv * 32 + g * 16 + rloc;
#pragma unroll
    for (int sub = 0; sub < 2; ++sub) {
      int c = sub * 4 + kg;
      a_rbyte[g][sub] = row_l * 128 + ((c ^ (row_l & 7)) << 4);
    }
  }
  int w_roff[8];
#pragma unroll
  for (int mt = 0; mt < 8; ++mt)
    w_roff[mt] = (mt * 16 + rloc) * 8;   // element offset within [kg] plane

  float4v accA[8], accB[8];              // g=0 / g=1 accumulators (static names)
#pragma unroll
  for (int mt = 0; mt < 8; ++mt) { accA[mt] = (float4v){0,0,0,0}; accB[mt] = (float4v){0,0,0,0}; }

  const char* wt_bytes = (const char*)Wt;
  const size_t amax = (size_t)N * K - 4;

  for (int s = s0; s < s1; ++s) {
    // ---- W: two 32k-tiles, one glds per thread per tile (linear src+dest) ----
#pragma unroll
    for (int i = 0; i < 2; ++i) {
      gload_lds16(wt_bytes + (size_t)(s * 2 + i) * 8192 + (size_t)t * 16,
                  (char*)lds_w + (size_t)i * 8192 + (size_t)(wv * 64) * 16);
    }
    // ---- A: 8 copy-like loads (1KB contiguous per wave-instr) ----
    float4v av[8];
    const int kb = s * 64;
#pragma unroll
    for (int p = 0; p < 8; ++p) {
      const float* src = apass[p] + kb;
      ptrdiff_t rel = src - A;
      av[p] = *(const float4v*)(A + (((size_t)rel > amax) ? amax : (size_t)rel));
    }
    // ---- cvt + swizzled LDS write (8B each) ----
#pragma unroll
    for (int p = 0; p < 8; ++p) {
      union { short4v v; __hip_bfloat16 h[4]; } pk;
      pk.h[0] = __float2bfloat16(av[p].x); pk.h[1] = __float2bfloat16(av[p].y);
      pk.h[2] = __float2bfloat16(av[p].z); pk.h[3] = __float2bfloat16(av[p].w);
      *(short4v*)((char*)lds_a + aw_byte[p]) = pk.v;
    }
    __syncthreads();

    // ---- compute: 2 subs x (2 afrag + 8 w-loads, 16 MFMA) ----
#pragma unroll
    for (int sub = 0; sub < 2; ++sub) {
      short8 afA = *(const short8*)((const char*)lds_a + a_rbyte[0][sub]);
      short8 afB = *(const short8*)((const char*)lds_a + a_rbyte[1][sub]);
      const __hip_bfloat16* lw = lds_w + sub * 4096 + kg * 1024;
#pragma unroll
      for (int mt = 0; mt < 8; ++mt) {
        short8 wfrag = *(const short8*)(lw + w_roff[mt]);
        accA[mt] = __builtin_amdgcn_mfma_f32_16x16x32_bf16(wfrag, afA, accA[mt], 0, 0, 0);
        accB[mt] = __builtin_amdgcn_mfma_f32_16x16x32_bf16(wfrag, afB, accB[mt], 0, 0, 0);
      }
    }
    __syncthreads();
  }

#pragma unroll
  for (int g = 0; g < 2; ++g) {
    int row = row_g0 + wv * 32 + g * 16 + rloc;
    if (row < N) {
      float* dst = Cp + (size_t)(rowoff + row) * 128 + kg * 4;
#pragma unroll
      for (int mt = 0; mt < 8; ++mt)
        *(float4v*)(dst + mt * 16) = (g == 0) ? accA[mt] : accB[mt];
    }
  }
}

// sum NP partials -> init (f32) + both sections of state (bf16)
template<int NP>
__global__ __launch_bounds__(256) void combineN(
    P12 parr, float4v* __restrict__ o_init, __hip_bfloat16* __restrict__ state,
    int n4, int NtD)
{
  int i = blockIdx.x * 256 + threadIdx.x;
  if (i >= n4) return;
  float4v s = ((const float4v*)parr.p[0])[i];
#pragma unroll
  for (int j = 1; j < NP; ++j) {
    float4v x = ((const float4v*)parr.p[j])[i];
    s.x += x.x; s.y += x.y; s.z += x.z; s.w += x.w;
  }
  o_init[i] = s;
  union { short4v v; __hip_bfloat16 h[4]; } b;
  b.h[0] = __float2bfloat16(s.x); b.h[1] = __float2bfloat16(s.y);
  b.h[2] = __float2bfloat16(s.z); b.h[3] = __float2bfloat16(s.w);
  *(short4v*)(state + (size_t)i * 4) = b.v;
  *(short4v*)(state + (size_t)NtD + (size_t)i * 4) = b.v;
}

// ---------------- gather core ----------------
template<int L, int PP>
__device__ __forceinline__ float gath(const __hip_bfloat16* __restrict__ sect,
                                      const int* __restrict__ paths,
                                      const float* __restrict__ pw, int n, int N, int d)
{
  float pwv[L];
#pragma unroll
  for (int l = 0; l < L; ++l) pwv[l] = pw[l * 128 + d];
  float acc = 0.f;
  const int* ip0 = paths + (size_t)n * L;
#pragma unroll
  for (int p = 0; p < PP; ++p) {
    const int* ip = ip0 + (size_t)p * N * L;
    int idx[L];
#pragma unroll
    for (int l = 0; l < L; ++l) idx[l] = ip[l];
#pragma unroll
    for (int l = 0; l < L; ++l)
      acc = fmaf(pwv[l], __bfloat162float(sect[(size_t)idx[l] * 128 + d]), acc);
  }
  return acc;
}

// ---------------- FUSED layer: gather 16 nodes -> LDS, then fc + residual ----------------
template<int LMM, int LMD, int PP>
__global__ __launch_bounds__(256) void layer_fused(
    const __hip_bfloat16* __restrict__ stateIn,
    const int* __restrict__ paths_mm, const int* __restrict__ paths_dd, const int* __restrict__ paths_md,
    const float* __restrict__ pw1l, const float* __restrict__ pw2l,
    const float* __restrict__ fcWl, const float* __restrict__ initb,
    __hip_bfloat16* __restrict__ stateOut,
    int Nm, int Nd, int nbm, int nbd)
{
  __shared__ float r_lds[16][128];
  const int t  = threadIdx.x;
  const int Nt = Nm + Nd;
  int b = blockIdx.x;

  const __hip_bfloat16* sect; const int* paths; const float* pw;
  int N, rowbase, nb; bool md;
  if (b < nbm)            { sect = stateIn;                     paths = paths_mm; pw = pw1l; N = Nm; rowbase = 0;  nb = b;             md = false; }
  else if (b < nbm + nbd) { sect = stateIn + (size_t)Nm * 128;  paths = paths_dd; pw = pw1l; N = Nd; rowbase = Nm; nb = b - nbm;       md = false; }
  else                    { sect = stateIn + (size_t)Nt * 128;  paths = paths_md; pw = pw2l; N = Nt; rowbase = Nt; nb = b - nbm - nbd; md = true;  }

  const int d   = t & 127;
  const int sub = t >> 7;
  const int n0  = nb * 16;

#pragma unroll
  for (int i = 0; i < 8; ++i) {
    int slot = sub + 2 * i;
    int n = n0 + slot;
    int ng = (n < N) ? n : (N - 1);
    float acc = md ? gath<LMD, PP>(sect, paths, pw, ng, N, d)
                   : gath<LMM, PP>(sect, paths, pw, ng, N, d);
    r_lds[slot][d] = acc * (1.0f / (float)PP);
  }
  __syncthreads();

  const int col = d;
  const int rh  = sub;
  float acc2[8];
#pragma unroll
  for (int j = 0; j < 8; ++j) acc2[j] = 0.f;
#pragma unroll 4
  for (int k = 0; k < 128; k += 8) {
    float w[8];
#pragma unroll
    for (int kk = 0; kk < 8; ++kk) w[kk] = fcWl[(size_t)(k + kk) * 128 + col];
#pragma unroll
    for (int j = 0; j < 8; ++j) {
      const float* rp = &r_lds[rh * 8 + j][k];
#pragma unroll
      for (int kk = 0; kk < 8; ++kk) acc2[j] = fmaf(rp[kk], w[kk], acc2[j]);
    }
  }
#pragma unroll
  for (int j = 0; j < 8; ++j) {
    int n = n0 + rh * 8 + j;
    if (n < N) {
      int rr = rowbase + n;
      int rbase = (rr < Nt) ? rr : rr - Nt;
      float v = ALPHA_ * initb[(size_t)rbase * 128 + col] + (1.f - ALPHA_) * fmaxf(acc2[j], 0.f);
      stateOut[(size_t)rr * 128 + col] = __float2bfloat16(v);
    }
  }
}

// ---------------- unfused fallbacks ----------------
__global__ __launch_bounds__(256) void gather_einsum_rt(
    const __hip_bfloat16* __restrict__ feats, const int* __restrict__ paths,
    const float* __restrict__ pw, float* __restrict__ r, int N, int P, int L)
{
  const int d = threadIdx.x & 127;
  const int n = blockIdx.x * 2 + (threadIdx.x >> 7);
  if (n >= N) return;
  float acc = 0.f;
  for (int p = 0; p < P; ++p) {
    const int* ip = paths + ((size_t)p * N + n) * L;
    for (int l = 0; l < L; ++l)
      acc = fmaf(pw[l * 128 + d], __bfloat162float(feats[(size_t)ip[l] * 128 + d]), acc);
  }
  r[(size_t)n * 128 + d] = acc * (1.0f / (float)P);
}

template<int TR>
__global__ __launch_bounds__(256) void fc_all(
    const float* __restrict__ Rm, const float* __restrict__ W,
    const float* __restrict__ initb, __hip_bfloat16* __restrict__ state, int Ntot, int Nt)
{
  const int col = threadIdx.x & 127;
  const int rh  = __builtin_amdgcn_readfirstlane((int)(threadIdx.x >> 7));
  const int row0 = blockIdx.x * (2 * TR) + rh * TR;
  const float* arow[TR];
#pragma unroll
  for (int r = 0; r < TR; ++r) {
    int rr = row0 + r; if (rr > Ntot - 1) rr = Ntot - 1;
    arow[r] = Rm + (size_t)rr * 128;
  }
  float acc[TR];
#pragma unroll
  for (int r = 0; r < TR; ++r) acc[r] = 0.f;
#pragma unroll 4
  for (int k = 0; k < 128; k += 8) {
    float w[8];
#pragma unroll
    for (int kk = 0; kk < 8; ++kk) w[kk] = W[(size_t)(k + kk) * 128 + col];
#pragma unroll
    for (int r = 0; r < TR; ++r) {
      const float* ap = arow[r] + k;
#pragma unroll
      for (int kk = 0; kk < 8; ++kk) acc[r] = fmaf(ap[kk], w[kk], acc[r]);
    }
  }
#pragma unroll
  for (int r = 0; r < TR; ++r) {
    int rr = row0 + r;
    if (rr < Ntot) {
      int rbase = (rr < Nt) ? rr : rr - Nt;
      float v = ALPHA_ * initb[(size_t)rbase * 128 + col] + (1.f - ALPHA_) * fmaxf(acc[r], 0.f);
      state[(size_t)rr * 128 + col] = __float2bfloat16(v);
    }
  }
}

// MLP collapse
__global__ void collapse1(const float* __restrict__ W0, const float* __restrict__ b0,
                          const float* __restrict__ W1, const float* __restrict__ b1,
                          float* __restrict__ w01, float* __restrict__ b01,
                          int E, int K0, int H1)
{
  int row = blockIdx.x; int c = threadIdx.x;
  if (c >= H1) return;
  const float* src; float base;
  if (row < E) { src = W0 + (size_t)row * K0; base = 0.f; }
  else         { src = b0; base = b1[c]; }
  float a0 = 0.f, a1 = 0.f, a2 = 0.f, a3 = 0.f;
#pragma unroll 4
  for (int k = 0; k < K0; k += 4) {
    a0 = fmaf(src[k + 0], W1[(size_t)(k + 0) * H1 + c], a0);
    a1 = fmaf(src[k + 1], W1[(size_t)(k + 1) * H1 + c], a1);
    a2 = fmaf(src[k + 2], W1[(size_t)(k + 2) * H1 + c], a2);
    a3 = fmaf(src[k + 3], W1[(size_t)(k + 3) * H1 + c], a3);
  }
  float acc = base + ((a0 + a1) + (a2 + a3));
  if (row < E) w01[(size_t)row * H1 + c] = acc; else b01[c] = acc;
}

__global__ void collapse2(const float* __restrict__ w01, const float* __restrict__ b01,
                          const float* __restrict__ W2, const float* __restrict__ b2,
                          float* __restrict__ w512, float* __restrict__ csc,
                          int E, int H1)
{
  int i = blockIdx.x * blockDim.x + threadIdx.x;
  if (i < E) {
    float a0 = 0.f, a1 = 0.f, a2 = 0.f, a3 = 0.f;
    for (int j = 0; j < H1; j += 4) {
      a0 = fmaf(w01[(size_t)i * H1 + j + 0], W2[j + 0], a0);
      a1 = fmaf(w01[(size_t)i * H1 + j + 1], W2[j + 1], a1);
      a2 = fmaf(w01[(size_t)i * H1 + j + 2], W2[j + 2], a2);
      a3 = fmaf(w01[(size_t)i * H1 + j + 3], W2[j + 3], a3);
    }
    w512[i] = (a0 + a1) + (a2 + a3);
  } else if (i == E) {
    float a = b2[0];
    for (int j = 0; j < H1; ++j) a = fmaf(b01[j], W2[j], a);
    csc[0] = a;
  }
}

__global__ __launch_bounds__(256) void node_partial(
    const __hip_bfloat16* __restrict__ Fmm, const __hip_bfloat16* __restrict__ Fdd,
    const __hip_bfloat16* __restrict__ Fmd,
    const float* __restrict__ w512, float* __restrict__ uv, int Nm, int Nt)
{
  int gid = blockIdx.x * blockDim.x + threadIdx.x;
  int wid = gid >> 6;
  int lane = threadIdx.x & 63;
  if (wid >= Nt) return;
  bool isM = wid < Nm;
  const __hip_bfloat16* X = isM ? (Fmm + (size_t)wid * 128) : (Fdd + (size_t)(wid - Nm) * 128);
  const __hip_bfloat16* Y = Fmd + (size_t)wid * 128;
  const float* w1 = w512 + (isM ? 0 : 256);
  const float* w2 = w1 + 128;
  float s = __bfloat162float(X[lane]) * w1[lane];
  s = fmaf(__bfloat162float(X[lane + 64]), w1[lane + 64], s);
  s = fmaf(__bfloat162float(Y[lane]), w2[lane], s);
  s = fmaf(__bfloat162float(Y[lane + 64]), w2[lane + 64], s);
#pragma unroll
  for (int off = 32; off > 0; off >>= 1) s += __shfl_down(s, off);
  if (lane == 0) uv[wid] = s;
}

__global__ __launch_bounds__(256) void score_kernel(
    const int* __restrict__ samples, const float* __restrict__ u, const float* __restrict__ v,
    const float* __restrict__ csc, float* __restrict__ out, int S)
{
  int s = blockIdx.x * blockDim.x + threadIdx.x;
  if (s >= S) return;
  const int2 ij = ((const int2*)samples)[s];
  float x = u[ij.x] + v[ij.y] + csc[0];
  out[s] = 1.0f / (1.0f + expf(-x));
}

extern "C" void kernel_launch(void* const* d_in, const int* in_sizes, int n_in,
                              void* d_out, int out_size, void* d_ws, size_t ws_size,
                              hipStream_t stream)
{
  const int*   paths_mm = (const int*)d_in[0];
  const int*   paths_dd = (const int*)d_in[1];
  const int*   paths_md = (const int*)d_in[2];
  const float* miRNA    = (const float*)d_in[3];
  const float* disease  = (const float*)d_in[4];
  const int*   samples  = (const int*)d_in[5];
  const float* Wm  = (const float*)d_in[6];
  const float* Wd  = (const float*)d_in[7];
  const float* pw1 = (const float*)d_in[8];
  const float* pw2 = (const float*)d_in[9];
  const float* fcW = (const float*)d_in[10];
  const float* W0  = (const float*)d_in[11];
  const float* b0  = (const float*)d_in[12];
  const float* W1  = (const float*)d_in[13];
  const float* b1  = (const float*)d_in[14];
  const float* W2  = (const float*)d_in[15];
  const float* b2  = (const float*)d_in[16];

  const int D  = 128;
  const int Nm = in_sizes[6] / D;
  const int Nd = in_sizes[7] / D;
  const int Nt = Nm + Nd;
  const int S  = in_sizes[5] / 2;
  const int layers = in_sizes[10] / (D * D);
  const int L1 = in_sizes[8] / (layers * D);
  const int L2 = in_sizes[9] / (layers * D);
  const int P  = in_sizes[0] / (Nm * L1);
  const int E  = 4 * D;
  const int K0 = in_sizes[12];
  const int H1 = in_sizes[14];
  const int Kpm = cdiv(Nm, 64) * 64;   // 8000
  const int Kpd = cdiv(Nd, 64) * 64;   // 6016
  const size_t NtD = (size_t)Nt * D;

  float* out = (float*)d_out;
  float* ws  = (float*)d_ws;
  size_t off = 0;
  float* init   = ws + off; off += NtD;                              // f32 summed init
  __hip_bfloat16* stateA = (__hip_bfloat16*)(ws + off); off += NtD;  // 2*NtD bf16
  __hip_bfloat16* stateB = (__hip_bfloat16*)(ws + off); off += NtD;  // 2*NtD bf16
  float* w01    = ws + off; off += (size_t)E * H1;
  float* b01    = ws + off; off += H1;
  float* w512   = ws + off; off += E;
  float* csc    = ws + off; off += 1;
  float* uv     = ws + off; off += Nt;
  __hip_bfloat16* WtTm = (__hip_bfloat16*)(ws + off); off += (size_t)D * Kpm / 2;
  __hip_bfloat16* WtTd = (__hip_bfloat16*)(ws + off); off += (size_t)D * Kpd / 2;
  float* pextra = ws + off;
  (void)n_in; (void)out_size;

  // 1. tile-major bf16 weight transposes
  make_wtT<<<Kpm / 32, 256, 0, stream>>>(Wm, WtTm, Nm);
  make_wtT<<<Kpd / 32, 256, 0, stream>>>(Wd, WtTd, Nd);

  // 2. MLP collapse
  collapse1<<<E + 1, 64, 0, stream>>>(W0, b0, W1, b1, w01, b01, E, K0, H1);
  collapse2<<<cdiv(E + 1, 256), 256, 0, stream>>>(w01, b01, W2, b2, w512, csc, E, H1);

  // 3. init GEMMs: BM=256 / BK=64 (halved W traffic), split-K sized to workspace
  {
    int nbm = cdiv(Nm, 256), nbd = cdiv(Nd, 256);
    int n4 = (int)(NtD / 4);
    P12 parr;
    parr.p[0] = init;
    parr.p[1] = (float*)stateB;      // free until layer 0 (combineN runs before layers)
    for (int j = 0; j < 10; ++j) parr.p[2 + j] = pextra + (size_t)j * NtD;
    if ((off + 7 * NtD) * 4 <= ws_size) {
      init_mfma6<9><<<(nbm + nbd) * 9, 512, 0, stream>>>(
          miRNA, WtTm, Nm, nbm, Kpm, disease, WtTd, Nd, Kpd, parr);
      combineN<9><<<cdiv(n4, 256), 256, 0, stream>>>(parr, (float4v*)init, stateA, n4, (int)NtD);
    } else if ((off + 4 * NtD) * 4 <= ws_size) {
      init_mfma6<6><<<(nbm + nbd) * 6, 512, 0, stream>>>(
          miRNA, WtTm, Nm, nbm, Kpm, disease, WtTd, Nd, Kpd, parr);
      combineN<6><<<cdiv(n4, 256), 256, 0, stream>>>(parr, (float4v*)init, stateA, n4, (int)NtD);
    } else {
      init_mfma6<3><<<(nbm + nbd) * 3, 512, 0, stream>>>(
          miRNA, WtTm, Nm, nbm, Kpm, disease, WtTd, Nd, Kpd, parr);
      combineN<3><<<cdiv(n4, 256), 256, 0, stream>>>(parr, (float4v*)init, stateA, n4, (int)NtD);
    }
  }

  // 4. path layers: fused gather+fc with ping-pong state
  const bool fuse_ok = (L1 == 4 && L2 == 6 && P == 8 &&
                        Nm % 16 == 0 && Nd % 16 == 0 && Nt % 16 == 0);
  __hip_bfloat16* cur = stateA;
  __hip_bfloat16* nxt = stateB;
  for (int l = 0; l < layers; ++l) {
    const float* pw1l = pw1 + (size_t)l * L1 * D;
    const float* pw2l = pw2 + (size_t)l * L2 * D;
    const float* fcWl = fcW + (size_t)l * D * D;
    if (fuse_ok) {
      int nbm16 = Nm / 16, nbd16 = Nd / 16, nbt16 = Nt / 16;
      layer_fused<4, 6, 8><<<nbm16 + nbd16 + nbt16, 256, 0, stream>>>(
          cur, paths_mm, paths_dd, paths_md, pw1l, pw2l, fcWl, init, nxt,
          Nm, Nd, nbm16, nbd16);
    } else {
      float* bufR = pextra;
      gather_einsum_rt<<<cdiv(Nm, 2), 256, 0, stream>>>(cur, paths_mm, pw1l, bufR, Nm, P, L1);
      gather_einsum_rt<<<cdiv(Nd, 2), 256, 0, stream>>>(cur + (size_t)Nm * D, paths_dd, pw1l,
                                                        bufR + (size_t)Nm * D, Nd, P, L1);
      gather_einsum_rt<<<cdiv(Nt, 2), 256, 0, stream>>>(cur + NtD, paths_md, pw2l,
                                                        bufR + NtD, Nt, P, L2);
      fc_all<8><<<cdiv(2 * Nt, 16), 256, 0, stream>>>(
          bufR, fcWl, init, nxt, 2 * Nt, Nt);
    }
    __hip_bfloat16* tmp = cur; cur = nxt; nxt = tmp;
  }

  // 5. per-node partial dots + scoring
  node_partial<<<cdiv(Nt * 64, 256), 256, 0, stream>>>(
      cur, cur + (size_t)Nm * D, cur + NtD, w512, uv, Nm, Nt);
  score_kernel<<<cdiv(S, 256), 256, 0, stream>>>(samples, uv, uv + Nm, csc, out, S);
}